// Round 9
// baseline (616.024 us; speedup 1.0000x reference)
//
#include <hip/hip_runtime.h>
#include <cstdint>
#include <cstddef>

#define SEQ 4096
#define DM  2048
#define NH  16
#define KVH 4
#define HD  128
// softmax scale folded into Q at RoPE time: 1/sqrt(128) * log2(e)
#define QSCALE (0.08838834764831845f * 1.4426950408889634f)

typedef short bf16_t;
typedef __attribute__((ext_vector_type(8))) short bf16x8;
typedef __attribute__((ext_vector_type(4))) float f32x4;
typedef __attribute__((ext_vector_type(4))) unsigned uint32x4;

__device__ __forceinline__ bf16_t f2b(float f) {
  unsigned u = __builtin_bit_cast(unsigned, f);
  u += 0x7fffu + ((u >> 16) & 1u);          // RNE
  return (bf16_t)(u >> 16);
}
__device__ __forceinline__ float b2f(bf16_t s) {
  unsigned u = ((unsigned)(unsigned short)s) << 16;
  return __builtin_bit_cast(float, u);
}
// v_cvt_pk_bf16_f32: packs 2 f32 -> 2 bf16 (RNE) in one instr (no builtin; T12)
__device__ __forceinline__ unsigned cvtpk(float lo, float hi) {
  unsigned r;
  asm("v_cvt_pk_bf16_f32 %0, %1, %2" : "=v"(r) : "v"(lo), "v"(hi));
  return r;
}

// async global->LDS, 16B per lane. LDS dest is wave-uniform base + lane*16
// (linear); swizzling is done by permuting the per-lane GLOBAL source.
__device__ __forceinline__ void gload_lds16(const void* gsrc, void* ldst) {
  __builtin_amdgcn_global_load_lds(
      (__attribute__((address_space(1))) void*)gsrc,
      (__attribute__((address_space(3))) void*)ldst, 16, 0, 0);
}

// ---------------- cast x -> bf16 ----------------
__global__ void cast_x_bf16(const float* __restrict__ x, bf16_t* __restrict__ xb, int n4) {
  int i = blockIdx.x * 256 + threadIdx.x;
  if (i >= n4) return;
  float4 v = ((const float4*)x)[i];
  union { bf16_t h[4]; unsigned long long u; } o;
  o.h[0] = f2b(v.x); o.h[1] = f2b(v.y); o.h[2] = f2b(v.z); o.h[3] = f2b(v.w);
  ((unsigned long long*)xb)[i] = o.u;
}

// ---------------- W [K][N] fp32 -> Wt [N][K] bf16 ----------------
__global__ void transpose_cast_w(const float* __restrict__ W, bf16_t* __restrict__ Wt,
                                 int K, int N) {
  __shared__ float tile[32][33];
  int k0 = blockIdx.y * 32, n0 = blockIdx.x * 32;
  int tx = threadIdx.x, ty = threadIdx.y;
#pragma unroll
  for (int dy = 0; dy < 32; dy += 8)
    tile[ty + dy][tx] = W[(size_t)(k0 + ty + dy) * N + n0 + tx];
  __syncthreads();
#pragma unroll
  for (int dy = 0; dy < 32; dy += 8)
    Wt[(size_t)(n0 + ty + dy) * K + k0 + tx] = f2b(tile[tx][ty + dy]);
}

// ---------------- RoPE cos/sin table ----------------
__global__ void rope_tab(float* __restrict__ ct, float* __restrict__ st) {
  int i = blockIdx.x * 256 + threadIdx.x;
  if (i >= SEQ * 64) return;
  int t = i >> 6, j = i & 63;
  float invf = expf(-(float)j * (9.210340371976184f / 64.0f)); // 10000^(-j/64)
  float ang = (float)t * invf;
  ct[i] = cosf(ang);
  st[i] = sinf(ang);
}

// ---------------- in-place RoPE on bf16 Q and K (Q pre-scaled) ----------------
__global__ void rope_apply(bf16_t* __restrict__ Qb, bf16_t* __restrict__ KVb,
                           const float* __restrict__ ct, const float* __restrict__ st) {
  int i = blockIdx.x * 256 + threadIdx.x;
  const int qtot = SEQ * NH * 64;
  const int tot = qtot + SEQ * KVH * 64;
  if (i >= tot) return;
  bf16_t* base; int t, j; float scl;
  if (i < qtot) {
    t = i >> 10; int rem = i & 1023; int hh = rem >> 6; j = rem & 63;
    base = Qb + (size_t)t * DM + hh * HD;
    scl = QSCALE;                              // fold softmax scale + log2e into Q
  } else {
    int i2 = i - qtot;
    t = i2 >> 8; int rem = i2 & 255; int hh = rem >> 6; j = rem & 63;
    base = KVb + (size_t)t * 1024 + hh * HD;   // K half = cols 0..511
    scl = 1.0f;
  }
  float c = ct[t * 64 + j], s = st[t * 64 + j];
  float x0 = b2f(base[j]);
  float x1 = b2f(base[j + 64]);
  base[j]      = f2b((x0 * c - x1 * s) * scl);
  base[j + 64] = f2b((x1 * c + x0 * s) * scl);
}

// ---------------- V half of KVb [T][1024] -> Vt [512][T], key-permuted ----------------
// Column index carries pi^-1 within each 64-key block:
//   pi(32a+8lg+4h+r) = 32a+16h+4lg+r  (PV A-slot -> true key, 16x16 pipeline)
// so P fragments after swapped-QK^T stay lane-local (pure register pack).
__global__ void transpose_v(const bf16_t* __restrict__ KVb, bf16_t* __restrict__ Vt) {
  __shared__ bf16_t tile[32][33];
  int t0 = blockIdx.y * 32, d0 = blockIdx.x * 32;
  int tx = threadIdx.x, ty = threadIdx.y;
#pragma unroll
  for (int dy = 0; dy < 32; dy += 8)
    tile[ty + dy][tx] = KVb[(size_t)(t0 + ty + dy) * 1024 + 512 + d0 + tx];
  __syncthreads();
  int tt = t0 + tx;
  int j = (tt & ~63) | (tt & 32) | ((tt & 12) << 1) | ((tt & 16) >> 2) | (tt & 3);
#pragma unroll
  for (int dy = 0; dy < 32; dy += 8)
    Vt[(size_t)(d0 + ty + dy) * SEQ + j] = tile[tx][ty + dy];
}

// ---------------- shared GEMM core: 128x128 tile, BK=64, 4 waves ----------------
// MODE 0: bf16 out, split at col 2048 -> C0 (stride 2048) / C1 (stride 1024)
// MODE 1: fp32 out + bias, single C0 (stride N)
template <int MODE>
__global__ __launch_bounds__(256, MODE == 0 ? 3 : 2)
void gemm_bt(const bf16_t* __restrict__ A, const bf16_t* __restrict__ Bt,
             void* __restrict__ C0out, void* __restrict__ C1out,
             const float* __restrict__ bias, int M, int N, int K) {
  __shared__ __align__(16) bf16_t ldsA[128 * 64];
  __shared__ __align__(16) bf16_t ldsB[128 * 64];
  const int t = threadIdx.x;
  const int w = t >> 6, l = t & 63;
  const int lg = l >> 4, lr = l & 15;
  const int bm = blockIdx.y, bn = blockIdx.x;
  const int wr = (w >> 1) * 64, wc = (w & 1) * 64;

  f32x4 acc[4][4] = {};

  for (int k0 = 0; k0 < K; k0 += 64) {
    __syncthreads();
#pragma unroll
    for (int i = 0; i < 4; ++i) {
      int idx = i * 256 + t;          // 0..1023, 16B granules
      int row = idx >> 3;             // 8 chunks per 64-col row
      int ch  = (idx & 7) ^ (row & 7);
      gload_lds16(A  + (size_t)(bm * 128 + row) * K + k0 + ch * 8, &ldsA[idx * 8]);
      gload_lds16(Bt + (size_t)(bn * 128 + row) * K + k0 + ch * 8, &ldsB[idx * 8]);
    }
    __syncthreads();
#pragma unroll
    for (int kk = 0; kk < 2; ++kk) {
      bf16x8 af[4], bfr[4];
#pragma unroll
      for (int m = 0; m < 4; ++m) {
        int row = wr + m * 16 + lr;
        int ch = (kk * 4 + lg) ^ (row & 7);
        af[m] = *(const bf16x8*)&ldsA[row * 64 + ch * 8];
      }
#pragma unroll
      for (int n = 0; n < 4; ++n) {
        int row = wc + n * 16 + lr;
        int ch = (kk * 4 + lg) ^ (row & 7);
        bfr[n] = *(const bf16x8*)&ldsB[row * 64 + ch * 8];
      }
#pragma unroll
      for (int m = 0; m < 4; ++m)
#pragma unroll
        for (int n = 0; n < 4; ++n)
          acc[m][n] = __builtin_amdgcn_mfma_f32_16x16x32_bf16(af[m], bfr[n], acc[m][n], 0, 0, 0);
    }
  }

  // D layout: col = lane&15, row = (lane>>4)*4 + r  [measured m89]
  const int row0 = bm * 128 + wr + lg * 4;
  if (MODE == 1) {
    float* C = (float*)C0out;
    const int col0 = bn * 128 + wc + lr;
#pragma unroll
    for (int n = 0; n < 4; ++n) {
      int col = col0 + n * 16;
      float b = bias[col];
#pragma unroll
      for (int m = 0; m < 4; ++m)
#pragma unroll
        for (int r = 0; r < 4; ++r)
          C[(size_t)(row0 + m * 16 + r) * N + col] = acc[m][n][r] + b;
    }
  } else {
    // QKV split: colbase is 64-aligned, regions 2048-aligned -> uniform branch
    const int colbase = bn * 128 + wc;
    bf16_t* C; int stride, cb;
    if (colbase < 2048) { C = (bf16_t*)C0out; stride = 2048; cb = colbase; }
    else                { C = (bf16_t*)C1out; stride = 1024; cb = colbase - 2048; }
#pragma unroll
    for (int m = 0; m < 4; ++m)
#pragma unroll
      for (int n = 0; n < 4; ++n) {
        int col = cb + n * 16 + lr;
#pragma unroll
        for (int r = 0; r < 4; ++r)
          C[(size_t)(row0 + m * 16 + r) * stride + col] = f2b(acc[m][n][r]);
      }
  }
}

// ---------------- causal flash attention ----------------
// 4 waves / 256 thr, ONE q-tile per block (qt = 63 - bx, heavy-first),
// grid (64, NH) = 1024 streaming blocks -> ~4-5 blocks/CU (LDS 32 KB).
// K double-buffered in LDS; V read DIRECT from global (L1-served: a block's
// 4 waves re-read the same 16 KB V-tile whose 128B lines span the tile keys).
// Swapped QK^T, key-permuted V (P in registers), ones-column row-sum,
// defer-max (THR=8), one barrier per KV tile.
__global__ __launch_bounds__(256, 4)
void attn_fwd(const bf16_t* __restrict__ Qb, const bf16_t* __restrict__ KVb,
              const bf16_t* __restrict__ Vt, bf16_t* __restrict__ ctx) {
  __shared__ __align__(16) bf16_t kt[2][64 * 128];     // K tiles, XOR-swizzled

  const int t = threadIdx.x;
  const int w = t >> 6, l = t & 63;
  const int lg = l >> 4, lr = l & 15;
  const int h = blockIdx.y, g = h >> 2;
  const int qt = 63 - blockIdx.x;           // heavy blocks dispatch first
  const int qrow0 = qt * 64 + w * 16;       // wave's first q-row

  // Q fragments (B-operand after swap; row/col = lane&15, k = (lane>>4)*8+i)
  bf16x8 qf[4];
#pragma unroll
  for (int kk = 0; kk < 4; ++kk)
    qf[kk] = *(const bf16x8*)&Qb[(size_t)(qrow0 + lr) * DM + h * HD + kk * 32 + lg * 8];

  f32x4 acc[9] = {};                        // [8] = row-sum (ones column)
  float m_run = -1e30f;                     // per-lane q-row = lr (scaled units)

  bf16x8 ones;
#pragma unroll
  for (int i = 0; i < 8; ++i) ones[i] = (short)0x3F80;  // bf16 1.0

  const bf16_t* ksrc = KVb + g * 128;
  const bf16_t* vsrc = Vt + (size_t)(g * 128) * SEQ;
  auto stage = [&](int buf, int kvt) {
#pragma unroll
    for (int i = 0; i < 4; ++i) {           // K [64][128]: 1024 granules, 16/row
      int idx = i * 256 + t;
      int row = idx >> 4;
      int ch = (idx & 15) ^ (row & 7);
      gload_lds16(ksrc + (size_t)(kvt * 64 + row) * 1024 + ch * 8, &kt[buf][idx * 8]);
    }
  };

  const int nkv = qt + 1;
  stage(0, 0);

  for (int kv = 0; kv < nkv; ++kv) {
    const int cur = kv & 1;
    const int kv0 = kv * 64;
    __syncthreads();                        // kt[cur] ready (vmcnt drained)
    if (kv + 1 < nkv) stage(cur ^ 1, kv + 1);

    // S^T = K Q^T (swapped): lane holds q = lr, key = kv0 + n*16 + lg*4 + r
    f32x4 s[4] = {};
    __builtin_amdgcn_s_setprio(1);
#pragma unroll
    for (int n = 0; n < 4; ++n) {
      int row = n * 16 + lr;
#pragma unroll
      for (int kk = 0; kk < 4; ++kk) {
        int ch = (kk * 4 + lg) ^ (row & 7);
        bf16x8 kf = *(const bf16x8*)&kt[cur][row * 128 + ch * 8];
        s[n] = __builtin_amdgcn_mfma_f32_16x16x32_bf16(kf, qf[kk], s[n], 0, 0, 0);
      }
    }
    __builtin_amdgcn_s_setprio(0);

    const int qrow = qrow0 + lr;
    if (kv == qt) {                         // diagonal tile: causal mask
#pragma unroll
      for (int n = 0; n < 4; ++n)
#pragma unroll
        for (int r = 0; r < 4; ++r) {
          int key = kv0 + n * 16 + lg * 4 + r;
          if (key > qrow) s[n][r] = -1e30f;
        }
    }

    // row max: in-lane over 16, then across the 4 lg lanes (xor 16, 32)
    float pm = s[0][0];
#pragma unroll
    for (int n = 0; n < 4; ++n)
#pragma unroll
      for (int r = 0; r < 4; ++r)
        pm = fmaxf(pm, s[n][r]);
    pm = fmaxf(pm, __shfl_xor(pm, 16, 64));
    pm = fmaxf(pm, __shfl_xor(pm, 32, 64));

    if (__any((int)(pm > m_run + 8.f))) {   // defer-max (T13)
      float mn = fmaxf(m_run, pm);
      float a_s = exp2f(m_run - mn);
      m_run = mn;
      float alpha[4];
#pragma unroll
      for (int r = 0; r < 4; ++r)           // broadcast to O-domain rows lg*4+r
        alpha[r] = __shfl(a_s, (l & 48) | (lg * 4 + r), 64);
#pragma unroll
      for (int nd = 0; nd < 9; ++nd)
#pragma unroll
        for (int r = 0; r < 4; ++r)
          acc[nd][r] *= alpha[r];
    }

    // P = exp2(s - m), packed to bf16 in registers (key-permuted V layout)
    unsigned u[8];
#pragma unroll
    for (int n = 0; n < 4; ++n) {
      u[2 * n]     = cvtpk(exp2f(s[n][0] - m_run), exp2f(s[n][1] - m_run));
      u[2 * n + 1] = cvtpk(exp2f(s[n][2] - m_run), exp2f(s[n][3] - m_run));
    }
    bf16x8 pf[2];
    pf[0] = __builtin_bit_cast(bf16x8, (uint32x4){u[0], u[1], u[2], u[3]});
    pf[1] = __builtin_bit_cast(bf16x8, (uint32x4){u[4], u[5], u[6], u[7]});

    // O += P * V; V fragments DIRECT from global (L1-resident tile),
    // key permutation is baked into Vt columns. Row-sum via ones column.
    __builtin_amdgcn_s_setprio(1);
#pragma unroll
    for (int kk2 = 0; kk2 < 2; ++kk2) {
#pragma unroll
      for (int nd = 0; nd < 8; ++nd) {
        bf16x8 vf = *(const bf16x8*)&vsrc[(size_t)(nd * 16 + lr) * SEQ + kv0 + kk2 * 32 + lg * 8];
        acc[nd] = __builtin_amdgcn_mfma_f32_16x16x32_bf16(pf[kk2], vf, acc[nd], 0, 0, 0);
      }
      acc[8] = __builtin_amdgcn_mfma_f32_16x16x32_bf16(pf[kk2], ones, acc[8], 0, 0, 0);
    }
    __builtin_amdgcn_s_setprio(0);
  }

#pragma unroll
  for (int r = 0; r < 4; ++r) {
    float rl = 1.0f / acc[8][r];
    int qrow = qrow0 + lg * 4 + r;
#pragma unroll
    for (int nd = 0; nd < 8; ++nd) {
      int col = h * HD + nd * 16 + lr;
      ctx[(size_t)qrow * DM + col] = f2b(acc[nd][r] * rl);
    }
  }
}

extern "C" void kernel_launch(void* const* d_in, const int* in_sizes, int n_in,
                              void* d_out, int out_size, void* d_ws, size_t ws_size,
                              hipStream_t stream) {
  const float* x  = (const float*)d_in[0];
  const float* Wq = (const float*)d_in[1];
  const float* Wk = (const float*)d_in[2];
  const float* Wv = (const float*)d_in[3];
  const float* Wo = (const float*)d_in[4];
  const float* bo = (const float*)d_in[5];
  float* out = (float*)d_out;

  char* p = (char*)d_ws;
  bf16_t* xb    = (bf16_t*)p;                         // also reused as ctx later
  bf16_t* ctx   = xb;                                 // xb dead after QKV GEMM
  p += (size_t)SEQ * DM * 2;                          // 16.8 MB
  bf16_t* Wqkvt = (bf16_t*)p; p += (size_t)3072 * DM * 2;     // 12.6 MB (Wq^T ++ Wk^T ++ Wv^T)
  bf16_t* Wot   = (bf16_t*)p; p += (size_t)DM * DM * 2;       // 8.4 MB
  bf16_t* Qb    = (bf16_t*)p; p += (size_t)SEQ * DM * 2;      // 16.8 MB
  bf16_t* KVb   = (bf16_t*)p; p += (size_t)SEQ * 1024 * 2;    // 8.4 MB
  bf16_t* Vt    = (bf16_t*)p; p += (size_t)512 * SEQ * 2;     // 4.2 MB
  float*  ctab  = (float*)p;  p += (size_t)SEQ * 64 * 4;      // 1 MB
  float*  stab  = (float*)p;  p += (size_t)SEQ * 64 * 4;      // 1 MB

  // 1. casts / transposes (Wq->rows 0..2047, Wk->2048..2559, Wv->2560..3071)
  cast_x_bf16<<<(SEQ * DM / 4 + 255) / 256, 256, 0, stream>>>(x, xb, SEQ * DM / 4);
  transpose_cast_w<<<dim3(DM / 32, DM / 32), dim3(32, 8), 0, stream>>>(Wq, Wqkvt, DM, DM);
  transpose_cast_w<<<dim3(512 / 32, DM / 32), dim3(32, 8), 0, stream>>>(Wk, Wqkvt + (size_t)2048 * DM, DM, 512);
  transpose_cast_w<<<dim3(512 / 32, DM / 32), dim3(32, 8), 0, stream>>>(Wv, Wqkvt + (size_t)2560 * DM, DM, 512);
  transpose_cast_w<<<dim3(DM / 32, DM / 32), dim3(32, 8), 0, stream>>>(Wo, Wot, DM, DM);
  rope_tab<<<(SEQ * 64 + 255) / 256, 256, 0, stream>>>(ctab, stab);

  // 2. fused QKV projection: N=3072, split outputs (768 blocks = 3/CU)
  gemm_bt<0><<<dim3(3072 / 128, SEQ / 128), 256, 0, stream>>>(
      xb, Wqkvt, Qb, KVb, nullptr, SEQ, 3072, DM);

  // 3. RoPE + V transpose (key-permuted layout)
  rope_apply<<<(SEQ * (NH + KVH) * 64 + 255) / 256, 256, 0, stream>>>(Qb, KVb, ctab, stab);
  transpose_v<<<dim3(512 / 32, SEQ / 32), dim3(32, 8), 0, stream>>>(KVb, Vt);

  // 4. attention (ctx aliases xb region — xb no longer needed)
  attn_fwd<<<dim3(64, NH), 256, 0, stream>>>(Qb, KVb, Vt, ctx);

  // 5. output projection + bias
  gemm_bt<1><<<dim3(DM / 128, SEQ / 128), 256, 0, stream>>>(
      ctx, Wot, out, nullptr, bo, SEQ, DM, DM);
}

// Round 10
// 283.557 us; speedup vs baseline: 2.1725x; 2.1725x over previous
//
#include <hip/hip_runtime.h>
#include <cstdint>
#include <cstddef>

#define SEQ 4096
#define DM  2048
#define NH  16
#define KVH 4
#define HD  128
// softmax scale folded into Q at RoPE time: 1/sqrt(128) * log2(e)
#define QSCALE (0.08838834764831845f * 1.4426950408889634f)

typedef short bf16_t;
typedef __attribute__((ext_vector_type(8))) short bf16x8;
typedef __attribute__((ext_vector_type(4))) float f32x4;
typedef __attribute__((ext_vector_type(4))) unsigned uint32x4;

__device__ __forceinline__ bf16_t f2b(float f) {
  unsigned u = __builtin_bit_cast(unsigned, f);
  u += 0x7fffu + ((u >> 16) & 1u);          // RNE
  return (bf16_t)(u >> 16);
}
__device__ __forceinline__ float b2f(bf16_t s) {
  unsigned u = ((unsigned)(unsigned short)s) << 16;
  return __builtin_bit_cast(float, u);
}
// v_cvt_pk_bf16_f32: packs 2 f32 -> 2 bf16 (RNE) in one instr (no builtin; T12)
__device__ __forceinline__ unsigned cvtpk(float lo, float hi) {
  unsigned r;
  asm("v_cvt_pk_bf16_f32 %0, %1, %2" : "=v"(r) : "v"(lo), "v"(hi));
  return r;
}

// async global->LDS, 16B per lane. LDS dest is wave-uniform base + lane*16
// (linear); swizzling is done by permuting the per-lane GLOBAL source.
__device__ __forceinline__ void gload_lds16(const void* gsrc, void* ldst) {
  __builtin_amdgcn_global_load_lds(
      (__attribute__((address_space(1))) void*)gsrc,
      (__attribute__((address_space(3))) void*)ldst, 16, 0, 0);
}

// ---------------- cast x -> bf16 ----------------
__global__ void cast_x_bf16(const float* __restrict__ x, bf16_t* __restrict__ xb, int n4) {
  int i = blockIdx.x * 256 + threadIdx.x;
  if (i >= n4) return;
  float4 v = ((const float4*)x)[i];
  union { bf16_t h[4]; unsigned long long u; } o;
  o.h[0] = f2b(v.x); o.h[1] = f2b(v.y); o.h[2] = f2b(v.z); o.h[3] = f2b(v.w);
  ((unsigned long long*)xb)[i] = o.u;
}

// ---------------- W [K][N] fp32 -> Wt [N][K] bf16 ----------------
__global__ void transpose_cast_w(const float* __restrict__ W, bf16_t* __restrict__ Wt,
                                 int K, int N) {
  __shared__ float tile[32][33];
  int k0 = blockIdx.y * 32, n0 = blockIdx.x * 32;
  int tx = threadIdx.x, ty = threadIdx.y;
#pragma unroll
  for (int dy = 0; dy < 32; dy += 8)
    tile[ty + dy][tx] = W[(size_t)(k0 + ty + dy) * N + n0 + tx];
  __syncthreads();
#pragma unroll
  for (int dy = 0; dy < 32; dy += 8)
    Wt[(size_t)(n0 + ty + dy) * K + k0 + tx] = f2b(tile[tx][ty + dy]);
}

// ---------------- RoPE cos/sin table ----------------
__global__ void rope_tab(float* __restrict__ ct, float* __restrict__ st) {
  int i = blockIdx.x * 256 + threadIdx.x;
  if (i >= SEQ * 64) return;
  int t = i >> 6, j = i & 63;
  float invf = expf(-(float)j * (9.210340371976184f / 64.0f)); // 10000^(-j/64)
  float ang = (float)t * invf;
  ct[i] = cosf(ang);
  st[i] = sinf(ang);
}

// ---------------- in-place RoPE on bf16 Q and K (Q pre-scaled) ----------------
__global__ void rope_apply(bf16_t* __restrict__ Qb, bf16_t* __restrict__ KVb,
                           const float* __restrict__ ct, const float* __restrict__ st) {
  int i = blockIdx.x * 256 + threadIdx.x;
  const int qtot = SEQ * NH * 64;
  const int tot = qtot + SEQ * KVH * 64;
  if (i >= tot) return;
  bf16_t* base; int t, j; float scl;
  if (i < qtot) {
    t = i >> 10; int rem = i & 1023; int hh = rem >> 6; j = rem & 63;
    base = Qb + (size_t)t * DM + hh * HD;
    scl = QSCALE;                              // fold softmax scale + log2e into Q
  } else {
    int i2 = i - qtot;
    t = i2 >> 8; int rem = i2 & 255; int hh = rem >> 6; j = rem & 63;
    base = KVb + (size_t)t * 1024 + hh * HD;   // K half = cols 0..511
    scl = 1.0f;
  }
  float c = ct[t * 64 + j], s = st[t * 64 + j];
  float x0 = b2f(base[j]);
  float x1 = b2f(base[j + 64]);
  base[j]      = f2b((x0 * c - x1 * s) * scl);
  base[j + 64] = f2b((x1 * c + x0 * s) * scl);
}

// ---------------- V half of KVb [T][1024] -> Vt [512][T], key-permuted ----------------
// Column index carries pi^-1 within each 64-key block:
//   pi(32a+8lg+4h+r) = 32a+16h+4lg+r  (PV A-slot -> true key, 16x16 pipeline)
// so P fragments after swapped-QK^T stay lane-local (pure register pack).
__global__ void transpose_v(const bf16_t* __restrict__ KVb, bf16_t* __restrict__ Vt) {
  __shared__ bf16_t tile[32][33];
  int t0 = blockIdx.y * 32, d0 = blockIdx.x * 32;
  int tx = threadIdx.x, ty = threadIdx.y;
#pragma unroll
  for (int dy = 0; dy < 32; dy += 8)
    tile[ty + dy][tx] = KVb[(size_t)(t0 + ty + dy) * 1024 + 512 + d0 + tx];
  __syncthreads();
  int tt = t0 + tx;
  int j = (tt & ~63) | (tt & 32) | ((tt & 12) << 1) | ((tt & 16) >> 2) | (tt & 3);
#pragma unroll
  for (int dy = 0; dy < 32; dy += 8)
    Vt[(size_t)(d0 + ty + dy) * SEQ + j] = tile[tx][ty + dy];
}

// ---------------- shared GEMM core: 128x128 tile, BK=64, 4 waves ----------------
// MODE 0: bf16 out, split at col 2048 -> C0 (stride 2048) / C1 (stride 1024)
// MODE 1: fp32 out + bias, single C0 (stride N)
template <int MODE>
__global__ __launch_bounds__(256, MODE == 0 ? 3 : 2)
void gemm_bt(const bf16_t* __restrict__ A, const bf16_t* __restrict__ Bt,
             void* __restrict__ C0out, void* __restrict__ C1out,
             const float* __restrict__ bias, int M, int N, int K) {
  __shared__ __align__(16) bf16_t ldsA[128 * 64];
  __shared__ __align__(16) bf16_t ldsB[128 * 64];
  const int t = threadIdx.x;
  const int w = t >> 6, l = t & 63;
  const int lg = l >> 4, lr = l & 15;
  const int bm = blockIdx.y, bn = blockIdx.x;
  const int wr = (w >> 1) * 64, wc = (w & 1) * 64;

  f32x4 acc[4][4] = {};

  for (int k0 = 0; k0 < K; k0 += 64) {
    __syncthreads();
#pragma unroll
    for (int i = 0; i < 4; ++i) {
      int idx = i * 256 + t;          // 0..1023, 16B granules
      int row = idx >> 3;             // 8 chunks per 64-col row
      int ch  = (idx & 7) ^ (row & 7);
      gload_lds16(A  + (size_t)(bm * 128 + row) * K + k0 + ch * 8, &ldsA[idx * 8]);
      gload_lds16(Bt + (size_t)(bn * 128 + row) * K + k0 + ch * 8, &ldsB[idx * 8]);
    }
    __syncthreads();
#pragma unroll
    for (int kk = 0; kk < 2; ++kk) {
      bf16x8 af[4], bfr[4];
#pragma unroll
      for (int m = 0; m < 4; ++m) {
        int row = wr + m * 16 + lr;
        int ch = (kk * 4 + lg) ^ (row & 7);
        af[m] = *(const bf16x8*)&ldsA[row * 64 + ch * 8];
      }
#pragma unroll
      for (int n = 0; n < 4; ++n) {
        int row = wc + n * 16 + lr;
        int ch = (kk * 4 + lg) ^ (row & 7);
        bfr[n] = *(const bf16x8*)&ldsB[row * 64 + ch * 8];
      }
#pragma unroll
      for (int m = 0; m < 4; ++m)
#pragma unroll
        for (int n = 0; n < 4; ++n)
          acc[m][n] = __builtin_amdgcn_mfma_f32_16x16x32_bf16(af[m], bfr[n], acc[m][n], 0, 0, 0);
    }
  }

  // D layout: col = lane&15, row = (lane>>4)*4 + r  [measured m89]
  const int row0 = bm * 128 + wr + lg * 4;
  if (MODE == 1) {
    float* C = (float*)C0out;
    const int col0 = bn * 128 + wc + lr;
#pragma unroll
    for (int n = 0; n < 4; ++n) {
      int col = col0 + n * 16;
      float b = bias[col];
#pragma unroll
      for (int m = 0; m < 4; ++m)
#pragma unroll
        for (int r = 0; r < 4; ++r)
          C[(size_t)(row0 + m * 16 + r) * N + col] = acc[m][n][r] + b;
    }
  } else {
    // QKV split: colbase is 64-aligned, regions 2048-aligned -> uniform branch
    const int colbase = bn * 128 + wc;
    bf16_t* C; int stride, cb;
    if (colbase < 2048) { C = (bf16_t*)C0out; stride = 2048; cb = colbase; }
    else                { C = (bf16_t*)C1out; stride = 1024; cb = colbase - 2048; }
#pragma unroll
    for (int m = 0; m < 4; ++m)
#pragma unroll
      for (int n = 0; n < 4; ++n) {
        int col = cb + n * 16 + lr;
#pragma unroll
        for (int r = 0; r < 4; ++r)
          C[(size_t)(row0 + m * 16 + r) * stride + col] = f2b(acc[m][n][r]);
      }
  }
}

// ---------------- causal flash attention (R8 + T15 delayed-PV pipeline) ----------------
// 8 waves / 512 threads; paired q-tiles (b, 63-b): waves 0-3 -> q-tile b,
// waves 4-7 -> q-tile 63-b (16 rows/wave) -> 4 waves/SIMD at 2 blocks/CU.
// T15: PV is delayed one tile — iteration t issues QK(t) (ds_read-bound MFMA)
// together with PV(t-1) (operand-ready MFMA) in one cluster, so PV fills
// QK's lgkmcnt stalls; softmax(t) then runs on VALU. PV(t-1) lands BEFORE
// iteration t's alpha-rescale, so acc and P stay in consistent m-units.
// V triple-buffered (lifetime 2 iters); K double-buffered. LDS = 80 KB.
__global__ __launch_bounds__(512, 4)
void attn_fwd(const bf16_t* __restrict__ Qb, const bf16_t* __restrict__ KVb,
              const bf16_t* __restrict__ Vt, bf16_t* __restrict__ ctx) {
  __shared__ __align__(16) bf16_t kt[2][64 * 128];     // K tiles, XOR-swizzled
  __shared__ __align__(16) bf16_t vts[3][128 * 64];    // V^T tiles (key-permuted), swizzled

  const int t = threadIdx.x;
  const int w = t >> 6, l = t & 63;
  const int lg = l >> 4, lr = l & 15;
  const int h = blockIdx.y, g = h >> 2;
  const int b = blockIdx.x;
  const int m = w >> 2, wq = w & 3;
  const int qt = m ? 63 - b : b;            // this wave's q-tile
  const int qrow0 = qt * 64 + wq * 16;      // wave's first q-row

  // Q fragments (B-operand after swap; row/col = lane&15, k = (lane>>4)*8+i)
  bf16x8 qf[4];
#pragma unroll
  for (int kk = 0; kk < 4; ++kk)
    qf[kk] = *(const bf16x8*)&Qb[(size_t)(qrow0 + lr) * DM + h * HD + kk * 32 + lg * 8];

  f32x4 acc[9] = {};                        // [8] = row-sum (ones column)
  float m_run = -1e30f;                     // per-lane q-row = lr (scaled units)
  bf16x8 pfp[2] = {};                       // P fragments of the PREVIOUS tile

  bf16x8 ones;
#pragma unroll
  for (int i = 0; i < 8; ++i) ones[i] = (short)0x3F80;  // bf16 1.0

  const bf16_t* ksrc = KVb + g * 128;
  const bf16_t* vsrc = Vt + (size_t)(g * 128) * SEQ;
  auto stage = [&](int kbuf, int vbuf, int kvt) {
#pragma unroll
    for (int i = 0; i < 2; ++i) {           // K [64][128]: 1024 granules, 16/row
      int idx = i * 512 + t;
      int row = idx >> 4;
      int ch = (idx & 15) ^ (row & 7);
      gload_lds16(ksrc + (size_t)(kvt * 64 + row) * 1024 + ch * 8, &kt[kbuf][idx * 8]);
    }
#pragma unroll
    for (int i = 0; i < 2; ++i) {           // V^T [128][64]: 1024 granules, 8/row
      int idx = i * 512 + t;
      int row = idx >> 3;
      int ch = (idx & 7) ^ (row & 7);
      gload_lds16(vsrc + (size_t)row * SEQ + kvt * 64 + ch * 8, &vts[vbuf][idx * 8]);
    }
  };

  const int nkv = 64 - b;                   // max tiles needed in this block
  stage(0, 0, 0);

  for (int kv = 0; kv < nkv; ++kv) {
    const int kcur = kv & 1;
    const int vprev = (kv + 2) % 3;         // == (kv-1) % 3 for kv >= 1
    const int kv0 = kv * 64;
    __syncthreads();                        // kt[kcur], vts[kv%3] ready
    if (kv + 1 < nkv) stage((kv + 1) & 1, (kv + 1) % 3, kv + 1);

    const bool act  = (kv <= qt);           // QK + softmax this tile
    const bool actp = (kv >= 1) && (kv - 1 <= qt);  // pending PV from prev tile

    // ---- MFMA cluster: QK(t) [ds_read-dependent] + PV(t-1) [ready] ----
    f32x4 s[4] = {};
    __builtin_amdgcn_s_setprio(1);
    if (act) {
#pragma unroll
      for (int n = 0; n < 4; ++n) {
        int row = n * 16 + lr;
#pragma unroll
        for (int kk = 0; kk < 4; ++kk) {
          int ch = (kk * 4 + lg) ^ (row & 7);
          bf16x8 kf = *(const bf16x8*)&kt[kcur][row * 128 + ch * 8];
          s[n] = __builtin_amdgcn_mfma_f32_16x16x32_bf16(kf, qf[kk], s[n], 0, 0, 0);
        }
      }
    }
    if (actp) {                             // completes tile kv-1's O update
#pragma unroll
      for (int kk2 = 0; kk2 < 2; ++kk2) {
#pragma unroll
        for (int nd = 0; nd < 8; ++nd) {
          int vrow = nd * 16 + lr;
          int vch = (kk2 * 4 + lg) ^ (lr & 7);
          bf16x8 vf = *(const bf16x8*)&vts[vprev][vrow * 64 + vch * 8];
          acc[nd] = __builtin_amdgcn_mfma_f32_16x16x32_bf16(pfp[kk2], vf, acc[nd], 0, 0, 0);
        }
        acc[8] = __builtin_amdgcn_mfma_f32_16x16x32_bf16(pfp[kk2], ones, acc[8], 0, 0, 0);
      }
    }
    __builtin_amdgcn_s_setprio(0);

    // ---- softmax(t): mask, max, defer-rescale (acc now includes PV(t-1)) ----
    if (act) {
      const int qrow = qrow0 + lr;
      if (kv == qt) {                       // diagonal tile: causal mask
#pragma unroll
        for (int n = 0; n < 4; ++n)
#pragma unroll
          for (int r = 0; r < 4; ++r) {
            int key = kv0 + n * 16 + lg * 4 + r;
            if (key > qrow) s[n][r] = -1e30f;
          }
      }

      float pm = s[0][0];
#pragma unroll
      for (int n = 0; n < 4; ++n)
#pragma unroll
        for (int r = 0; r < 4; ++r)
          pm = fmaxf(pm, s[n][r]);
      pm = fmaxf(pm, __shfl_xor(pm, 16, 64));
      pm = fmaxf(pm, __shfl_xor(pm, 32, 64));

      if (__any((int)(pm > m_run + 8.f))) { // defer-max (T13)
        float mn = fmaxf(m_run, pm);
        float a_s = exp2f(m_run - mn);
        m_run = mn;
        float alpha[4];
#pragma unroll
        for (int r = 0; r < 4; ++r)         // broadcast to O-domain rows lg*4+r
          alpha[r] = __shfl(a_s, (l & 48) | (lg * 4 + r), 64);
#pragma unroll
        for (int nd = 0; nd < 9; ++nd)
#pragma unroll
          for (int r = 0; r < 4; ++r)
            acc[nd][r] *= alpha[r];
      }

      // P = exp2(s - m), packed to bf16 (key-permuted V layout), held for t+1
      unsigned u[8];
#pragma unroll
      for (int n = 0; n < 4; ++n) {
        u[2 * n]     = cvtpk(exp2f(s[n][0] - m_run), exp2f(s[n][1] - m_run));
        u[2 * n + 1] = cvtpk(exp2f(s[n][2] - m_run), exp2f(s[n][3] - m_run));
      }
      pfp[0] = __builtin_bit_cast(bf16x8, (uint32x4){u[0], u[1], u[2], u[3]});
      pfp[1] = __builtin_bit_cast(bf16x8, (uint32x4){u[4], u[5], u[6], u[7]});
    }
  }

  // ---- drain: heavy waves (qt == nkv-1) still owe PV(nkv-1) ----
  if (qt == nkv - 1) {
    const int vlast = (nkv - 1) % 3;
    __builtin_amdgcn_s_setprio(1);
#pragma unroll
    for (int kk2 = 0; kk2 < 2; ++kk2) {
#pragma unroll
      for (int nd = 0; nd < 8; ++nd) {
        int vrow = nd * 16 + lr;
        int vch = (kk2 * 4 + lg) ^ (lr & 7);
        bf16x8 vf = *(const bf16x8*)&vts[vlast][vrow * 64 + vch * 8];
        acc[nd] = __builtin_amdgcn_mfma_f32_16x16x32_bf16(pfp[kk2], vf, acc[nd], 0, 0, 0);
      }
      acc[8] = __builtin_amdgcn_mfma_f32_16x16x32_bf16(pfp[kk2], ones, acc[8], 0, 0, 0);
    }
    __builtin_amdgcn_s_setprio(0);
  }

#pragma unroll
  for (int r = 0; r < 4; ++r) {
    float rl = 1.0f / acc[8][r];
    int qrow = qrow0 + lg * 4 + r;
#pragma unroll
    for (int nd = 0; nd < 8; ++nd) {
      int col = h * HD + nd * 16 + lr;
      ctx[(size_t)qrow * DM + col] = f2b(acc[nd][r] * rl);
    }
  }
}

extern "C" void kernel_launch(void* const* d_in, const int* in_sizes, int n_in,
                              void* d_out, int out_size, void* d_ws, size_t ws_size,
                              hipStream_t stream) {
  const float* x  = (const float*)d_in[0];
  const float* Wq = (const float*)d_in[1];
  const float* Wk = (const float*)d_in[2];
  const float* Wv = (const float*)d_in[3];
  const float* Wo = (const float*)d_in[4];
  const float* bo = (const float*)d_in[5];
  float* out = (float*)d_out;

  char* p = (char*)d_ws;
  bf16_t* xb    = (bf16_t*)p;                         // also reused as ctx later
  bf16_t* ctx   = xb;                                 // xb dead after QKV GEMM
  p += (size_t)SEQ * DM * 2;                          // 16.8 MB
  bf16_t* Wqkvt = (bf16_t*)p; p += (size_t)3072 * DM * 2;     // 12.6 MB (Wq^T ++ Wk^T ++ Wv^T)
  bf16_t* Wot   = (bf16_t*)p; p += (size_t)DM * DM * 2;       // 8.4 MB
  bf16_t* Qb    = (bf16_t*)p; p += (size_t)SEQ * DM * 2;      // 16.8 MB
  bf16_t* KVb   = (bf16_t*)p; p += (size_t)SEQ * 1024 * 2;    // 8.4 MB
  bf16_t* Vt    = (bf16_t*)p; p += (size_t)512 * SEQ * 2;     // 4.2 MB
  float*  ctab  = (float*)p;  p += (size_t)SEQ * 64 * 4;      // 1 MB
  float*  stab  = (float*)p;  p += (size_t)SEQ * 64 * 4;      // 1 MB

  // 1. casts / transposes (Wq->rows 0..2047, Wk->2048..2559, Wv->2560..3071)
  cast_x_bf16<<<(SEQ * DM / 4 + 255) / 256, 256, 0, stream>>>(x, xb, SEQ * DM / 4);
  transpose_cast_w<<<dim3(DM / 32, DM / 32), dim3(32, 8), 0, stream>>>(Wq, Wqkvt, DM, DM);
  transpose_cast_w<<<dim3(512 / 32, DM / 32), dim3(32, 8), 0, stream>>>(Wk, Wqkvt + (size_t)2048 * DM, DM, 512);
  transpose_cast_w<<<dim3(512 / 32, DM / 32), dim3(32, 8), 0, stream>>>(Wv, Wqkvt + (size_t)2560 * DM, DM, 512);
  transpose_cast_w<<<dim3(DM / 32, DM / 32), dim3(32, 8), 0, stream>>>(Wo, Wot, DM, DM);
  rope_tab<<<(SEQ * 64 + 255) / 256, 256, 0, stream>>>(ctab, stab);

  // 2. fused QKV projection: N=3072, split outputs (768 blocks = 3/CU)
  gemm_bt<0><<<dim3(3072 / 128, SEQ / 128), 256, 0, stream>>>(
      xb, Wqkvt, Qb, KVb, nullptr, SEQ, 3072, DM);

  // 3. RoPE + V transpose (key-permuted layout)
  rope_apply<<<(SEQ * (NH + KVH) * 64 + 255) / 256, 256, 0, stream>>>(Qb, KVb, ctab, stab);
  transpose_v<<<dim3(512 / 32, SEQ / 32), dim3(32, 8), 0, stream>>>(KVb, Vt);

  // 4. attention (ctx aliases xb region — xb no longer needed)
  attn_fwd<<<dim3(32, NH), 512, 0, stream>>>(Qb, KVb, Vt, ctx);

  // 5. output projection + bias
  gemm_bt<1><<<dim3(DM / 128, SEQ / 128), 256, 0, stream>>>(
      ctx, Wot, out, nullptr, bo, SEQ, DM, DM);
}

// Round 11
// 264.958 us; speedup vs baseline: 2.3250x; 1.0702x over previous
//
#include <hip/hip_runtime.h>
#include <cstdint>
#include <cstddef>

#define SEQ 4096
#define DM  2048
#define NH  16
#define KVH 4
#define HD  128
// softmax scale folded into Q at RoPE time: 1/sqrt(128) * log2(e)
#define QSCALE (0.08838834764831845f * 1.4426950408889634f)

typedef short bf16_t;
typedef __attribute__((ext_vector_type(8))) short bf16x8;
typedef __attribute__((ext_vector_type(4))) float f32x4;
typedef __attribute__((ext_vector_type(4))) unsigned uint32x4;

__device__ __forceinline__ bf16_t f2b(float f) {
  unsigned u = __builtin_bit_cast(unsigned, f);
  u += 0x7fffu + ((u >> 16) & 1u);          // RNE
  return (bf16_t)(u >> 16);
}
__device__ __forceinline__ float b2f(bf16_t s) {
  unsigned u = ((unsigned)(unsigned short)s) << 16;
  return __builtin_bit_cast(float, u);
}
// v_cvt_pk_bf16_f32: packs 2 f32 -> 2 bf16 (RNE) in one instr (no builtin; T12)
__device__ __forceinline__ unsigned cvtpk(float lo, float hi) {
  unsigned r;
  asm("v_cvt_pk_bf16_f32 %0, %1, %2" : "=v"(r) : "v"(lo), "v"(hi));
  return r;
}

// async global->LDS, 16B per lane. LDS dest is wave-uniform base + lane*16
// (linear); swizzling is done by permuting the per-lane GLOBAL source.
__device__ __forceinline__ void gload_lds16(const void* gsrc, void* ldst) {
  __builtin_amdgcn_global_load_lds(
      (__attribute__((address_space(1))) void*)gsrc,
      (__attribute__((address_space(3))) void*)ldst, 16, 0, 0);
}

// ---------------- cast x -> bf16 ----------------
__global__ void cast_x_bf16(const float* __restrict__ x, bf16_t* __restrict__ xb, int n4) {
  int i = blockIdx.x * 256 + threadIdx.x;
  if (i >= n4) return;
  float4 v = ((const float4*)x)[i];
  union { bf16_t h[4]; unsigned long long u; } o;
  o.h[0] = f2b(v.x); o.h[1] = f2b(v.y); o.h[2] = f2b(v.z); o.h[3] = f2b(v.w);
  ((unsigned long long*)xb)[i] = o.u;
}

// ---------------- W [K][N] fp32 -> Wt [N][K] bf16 ----------------
__global__ void transpose_cast_w(const float* __restrict__ W, bf16_t* __restrict__ Wt,
                                 int K, int N) {
  __shared__ float tile[32][33];
  int k0 = blockIdx.y * 32, n0 = blockIdx.x * 32;
  int tx = threadIdx.x, ty = threadIdx.y;
#pragma unroll
  for (int dy = 0; dy < 32; dy += 8)
    tile[ty + dy][tx] = W[(size_t)(k0 + ty + dy) * N + n0 + tx];
  __syncthreads();
#pragma unroll
  for (int dy = 0; dy < 32; dy += 8)
    Wt[(size_t)(n0 + ty + dy) * K + k0 + tx] = f2b(tile[tx][ty + dy]);
}

// ---------------- RoPE cos/sin table ----------------
__global__ void rope_tab(float* __restrict__ ct, float* __restrict__ st) {
  int i = blockIdx.x * 256 + threadIdx.x;
  if (i >= SEQ * 64) return;
  int t = i >> 6, j = i & 63;
  float invf = expf(-(float)j * (9.210340371976184f / 64.0f)); // 10000^(-j/64)
  float ang = (float)t * invf;
  ct[i] = cosf(ang);
  st[i] = sinf(ang);
}

// ---------------- in-place RoPE on bf16 Q and K (Q pre-scaled), VECTORIZED ----------------
// Each thread rotates 8 (j, j+64) pairs: 2x bf16x8 loads, 4x float4 table
// loads, 2x bf16x8 stores (16B/lane coalesced; G13).
__global__ void rope_apply(bf16_t* __restrict__ Qb, bf16_t* __restrict__ KVb,
                           const float* __restrict__ ct, const float* __restrict__ st) {
  int i = blockIdx.x * 256 + threadIdx.x;
  const int qtot = SEQ * NH * 8;            // 8 j8-chunks per (t, head)
  const int tot = qtot + SEQ * KVH * 8;
  if (i >= tot) return;
  bf16_t* base; int t, j8; float scl;
  if (i < qtot) {
    t = i >> 7; int rem = i & 127; int hh = rem >> 3; j8 = (rem & 7) * 8;
    base = Qb + (size_t)t * DM + hh * HD;
    scl = QSCALE;                            // fold softmax scale + log2e into Q
  } else {
    int i2 = i - qtot;
    t = i2 >> 5; int rem = i2 & 31; int hh = rem >> 3; j8 = (rem & 7) * 8;
    base = KVb + (size_t)t * 1024 + hh * HD; // K half = cols 0..511
    scl = 1.0f;
  }
  bf16x8 x0 = *(const bf16x8*)&base[j8];
  bf16x8 x1 = *(const bf16x8*)&base[j8 + 64];
  float4 c0 = *(const float4*)&ct[t * 64 + j8];
  float4 c1 = *(const float4*)&ct[t * 64 + j8 + 4];
  float4 s0 = *(const float4*)&st[t * 64 + j8];
  float4 s1 = *(const float4*)&st[t * 64 + j8 + 4];
  float c[8] = {c0.x, c0.y, c0.z, c0.w, c1.x, c1.y, c1.z, c1.w};
  float s[8] = {s0.x, s0.y, s0.z, s0.w, s1.x, s1.y, s1.z, s1.w};
  bf16x8 o0, o1;
#pragma unroll
  for (int r = 0; r < 8; ++r) {
    float a = b2f(x0[r]), b = b2f(x1[r]);
    o0[r] = f2b((a * c[r] - b * s[r]) * scl);
    o1[r] = f2b((b * c[r] + a * s[r]) * scl);
  }
  *(bf16x8*)&base[j8]      = o0;
  *(bf16x8*)&base[j8 + 64] = o1;
}

// ---------------- V half of KVb [T][1024] -> Vt [512][T], key-permuted ----------------
// Column index carries pi^-1 within each 64-key block:
//   pi(32a+8lg+4h+r) = 32a+16h+4lg+r  (PV A-slot -> true key, 16x16 pipeline)
// so P fragments after swapped-QK^T stay lane-local (pure register pack).
__global__ void transpose_v(const bf16_t* __restrict__ KVb, bf16_t* __restrict__ Vt) {
  __shared__ bf16_t tile[32][33];
  int t0 = blockIdx.y * 32, d0 = blockIdx.x * 32;
  int tx = threadIdx.x, ty = threadIdx.y;
#pragma unroll
  for (int dy = 0; dy < 32; dy += 8)
    tile[ty + dy][tx] = KVb[(size_t)(t0 + ty + dy) * 1024 + 512 + d0 + tx];
  __syncthreads();
  int tt = t0 + tx;
  int j = (tt & ~63) | (tt & 32) | ((tt & 12) << 1) | ((tt & 16) >> 2) | (tt & 3);
#pragma unroll
  for (int dy = 0; dy < 32; dy += 8)
    Vt[(size_t)(d0 + ty + dy) * SEQ + j] = tile[tx][ty + dy];
}

// ---------------- shared GEMM core: 128x128 tile, BK=64, 4 waves ----------------
// MODE 0: bf16 out, split at col 2048 -> C0 (stride 2048) / C1 (stride 1024)
// MODE 1: fp32 out + bias, single C0 (stride N)
template <int MODE>
__global__ __launch_bounds__(256, MODE == 0 ? 3 : 2)
void gemm_bt(const bf16_t* __restrict__ A, const bf16_t* __restrict__ Bt,
             void* __restrict__ C0out, void* __restrict__ C1out,
             const float* __restrict__ bias, int M, int N, int K) {
  __shared__ __align__(16) bf16_t ldsA[128 * 64];
  __shared__ __align__(16) bf16_t ldsB[128 * 64];
  const int t = threadIdx.x;
  const int w = t >> 6, l = t & 63;
  const int lg = l >> 4, lr = l & 15;
  const int bm = blockIdx.y, bn = blockIdx.x;
  const int wr = (w >> 1) * 64, wc = (w & 1) * 64;

  f32x4 acc[4][4] = {};

  for (int k0 = 0; k0 < K; k0 += 64) {
    __syncthreads();
#pragma unroll
    for (int i = 0; i < 4; ++i) {
      int idx = i * 256 + t;          // 0..1023, 16B granules
      int row = idx >> 3;             // 8 chunks per 64-col row
      int ch  = (idx & 7) ^ (row & 7);
      gload_lds16(A  + (size_t)(bm * 128 + row) * K + k0 + ch * 8, &ldsA[idx * 8]);
      gload_lds16(Bt + (size_t)(bn * 128 + row) * K + k0 + ch * 8, &ldsB[idx * 8]);
    }
    __syncthreads();
#pragma unroll
    for (int kk = 0; kk < 2; ++kk) {
      bf16x8 af[4], bfr[4];
#pragma unroll
      for (int m = 0; m < 4; ++m) {
        int row = wr + m * 16 + lr;
        int ch = (kk * 4 + lg) ^ (row & 7);
        af[m] = *(const bf16x8*)&ldsA[row * 64 + ch * 8];
      }
#pragma unroll
      for (int n = 0; n < 4; ++n) {
        int row = wc + n * 16 + lr;
        int ch = (kk * 4 + lg) ^ (row & 7);
        bfr[n] = *(const bf16x8*)&ldsB[row * 64 + ch * 8];
      }
#pragma unroll
      for (int m = 0; m < 4; ++m)
#pragma unroll
        for (int n = 0; n < 4; ++n)
          acc[m][n] = __builtin_amdgcn_mfma_f32_16x16x32_bf16(af[m], bfr[n], acc[m][n], 0, 0, 0);
    }
  }

  // D layout: col = lane&15, row = (lane>>4)*4 + r  [measured m89]
  const int row0 = bm * 128 + wr + lg * 4;
  if (MODE == 1) {
    float* C = (float*)C0out;
    const int col0 = bn * 128 + wc + lr;
#pragma unroll
    for (int n = 0; n < 4; ++n) {
      int col = col0 + n * 16;
      float b = bias[col];
#pragma unroll
      for (int m = 0; m < 4; ++m)
#pragma unroll
        for (int r = 0; r < 4; ++r)
          C[(size_t)(row0 + m * 16 + r) * N + col] = acc[m][n][r] + b;
    }
  } else {
    // QKV split: colbase is 64-aligned, regions 2048-aligned -> uniform branch
    const int colbase = bn * 128 + wc;
    bf16_t* C; int stride, cb;
    if (colbase < 2048) { C = (bf16_t*)C0out; stride = 2048; cb = colbase; }
    else                { C = (bf16_t*)C1out; stride = 1024; cb = colbase - 2048; }
#pragma unroll
    for (int m = 0; m < 4; ++m)
#pragma unroll
      for (int n = 0; n < 4; ++n) {
        int col = cb + n * 16 + lr;
#pragma unroll
        for (int r = 0; r < 4; ++r)
          C[(size_t)(row0 + m * 16 + r) * stride + col] = f2b(acc[m][n][r]);
      }
  }
}

// ---------------- causal flash attention (R8 structure, verified 135 us) ----------------
// 8 waves / 512 threads per block; paired q-tiles (b, 63-b): waves 0-3 own
// q-tile b (16 rows each), waves 4-7 own q-tile 63-b -> 4 waves/SIMD at
// 2 blocks/CU. Swapped QK^T, key-permuted V (P in registers), ones-column
// row-sum, defer-max (THR=8), K+V double-buffered LDS, one barrier per tile.
__global__ __launch_bounds__(512, 4)
void attn_fwd(const bf16_t* __restrict__ Qb, const bf16_t* __restrict__ KVb,
              const bf16_t* __restrict__ Vt, bf16_t* __restrict__ ctx) {
  __shared__ __align__(16) bf16_t kt[2][64 * 128];     // K tiles, XOR-swizzled
  __shared__ __align__(16) bf16_t vts[2][128 * 64];    // V^T tiles (key-permuted), swizzled

  const int t = threadIdx.x;
  const int w = t >> 6, l = t & 63;
  const int lg = l >> 4, lr = l & 15;
  const int h = blockIdx.y, g = h >> 2;
  const int b = blockIdx.x;
  const int m = w >> 2, wq = w & 3;
  const int qt = m ? 63 - b : b;            // this wave's q-tile
  const int qrow0 = qt * 64 + wq * 16;      // wave's first q-row

  // Q fragments (B-operand after swap; row/col = lane&15, k = (lane>>4)*8+i)
  bf16x8 qf[4];
#pragma unroll
  for (int kk = 0; kk < 4; ++kk)
    qf[kk] = *(const bf16x8*)&Qb[(size_t)(qrow0 + lr) * DM + h * HD + kk * 32 + lg * 8];

  f32x4 acc[9] = {};                        // [8] = row-sum (ones column)
  float m_run = -1e30f;                     // per-lane q-row = lr (scaled units)

  bf16x8 ones;
#pragma unroll
  for (int i = 0; i < 8; ++i) ones[i] = (short)0x3F80;  // bf16 1.0

  const bf16_t* ksrc = KVb + g * 128;
  const bf16_t* vsrc = Vt + (size_t)(g * 128) * SEQ;
  auto stage = [&](int buf, int kvt) {
#pragma unroll
    for (int i = 0; i < 2; ++i) {           // K [64][128]: 1024 granules, 16/row
      int idx = i * 512 + t;
      int row = idx >> 4;
      int ch = (idx & 15) ^ (row & 7);
      gload_lds16(ksrc + (size_t)(kvt * 64 + row) * 1024 + ch * 8, &kt[buf][idx * 8]);
    }
#pragma unroll
    for (int i = 0; i < 2; ++i) {           // V^T [128][64]: 1024 granules, 8/row
      int idx = i * 512 + t;
      int row = idx >> 3;
      int ch = (idx & 7) ^ (row & 7);
      gload_lds16(vsrc + (size_t)row * SEQ + kvt * 64 + ch * 8, &vts[buf][idx * 8]);
    }
  };

  const int nkv = 64 - b;                   // qt1 + 1
  stage(0, 0);

  for (int kv = 0; kv < nkv; ++kv) {
    const int cur = kv & 1;
    const int kv0 = kv * 64;
    __syncthreads();                        // kt/vts[cur] ready (vmcnt drained)
    if (kv + 1 < nkv) stage(cur ^ 1, kv + 1);

    if (kv <= qt) {                         // causal: tile active for this wave
      // S^T = K Q^T (swapped): lane holds q = lr, key = kv0 + n*16 + lg*4 + r
      f32x4 s[4] = {};
      __builtin_amdgcn_s_setprio(1);
#pragma unroll
      for (int n = 0; n < 4; ++n) {
        int row = n * 16 + lr;
#pragma unroll
        for (int kk = 0; kk < 4; ++kk) {
          int ch = (kk * 4 + lg) ^ (row & 7);
          bf16x8 kf = *(const bf16x8*)&kt[cur][row * 128 + ch * 8];
          s[n] = __builtin_amdgcn_mfma_f32_16x16x32_bf16(kf, qf[kk], s[n], 0, 0, 0);
        }
      }
      __builtin_amdgcn_s_setprio(0);

      const int qrow = qrow0 + lr;
      if (kv == qt) {                       // diagonal tile: causal mask
#pragma unroll
        for (int n = 0; n < 4; ++n)
#pragma unroll
          for (int r = 0; r < 4; ++r) {
            int key = kv0 + n * 16 + lg * 4 + r;
            if (key > qrow) s[n][r] = -1e30f;
          }
      }

      // row max: in-lane over 16, then across the 4 lg lanes (xor 16, 32)
      float pm = s[0][0];
#pragma unroll
      for (int n = 0; n < 4; ++n)
#pragma unroll
        for (int r = 0; r < 4; ++r)
          pm = fmaxf(pm, s[n][r]);
      pm = fmaxf(pm, __shfl_xor(pm, 16, 64));
      pm = fmaxf(pm, __shfl_xor(pm, 32, 64));

      if (__any((int)(pm > m_run + 8.f))) { // defer-max (T13)
        float mn = fmaxf(m_run, pm);
        float a_s = exp2f(m_run - mn);
        m_run = mn;
        float alpha[4];
#pragma unroll
        for (int r = 0; r < 4; ++r)         // broadcast to O-domain rows lg*4+r
          alpha[r] = __shfl(a_s, (l & 48) | (lg * 4 + r), 64);
#pragma unroll
        for (int nd = 0; nd < 9; ++nd)
#pragma unroll
          for (int r = 0; r < 4; ++r)
            acc[nd][r] *= alpha[r];
      }

      // P = exp2(s - m), packed to bf16 in registers (key-permuted V layout)
      unsigned u[8];
#pragma unroll
      for (int n = 0; n < 4; ++n) {
        u[2 * n]     = cvtpk(exp2f(s[n][0] - m_run), exp2f(s[n][1] - m_run));
        u[2 * n + 1] = cvtpk(exp2f(s[n][2] - m_run), exp2f(s[n][3] - m_run));
      }
      bf16x8 pf[2];
      pf[0] = __builtin_bit_cast(bf16x8, (uint32x4){u[0], u[1], u[2], u[3]});
      pf[1] = __builtin_bit_cast(bf16x8, (uint32x4){u[4], u[5], u[6], u[7]});

      // O += P * V; row-sum via ones column
      __builtin_amdgcn_s_setprio(1);
#pragma unroll
      for (int kk2 = 0; kk2 < 2; ++kk2) {
#pragma unroll
        for (int nd = 0; nd < 8; ++nd) {
          int vrow = nd * 16 + lr;
          int vch = (kk2 * 4 + lg) ^ (lr & 7);
          bf16x8 vf = *(const bf16x8*)&vts[cur][vrow * 64 + vch * 8];
          acc[nd] = __builtin_amdgcn_mfma_f32_16x16x32_bf16(pf[kk2], vf, acc[nd], 0, 0, 0);
        }
        acc[8] = __builtin_amdgcn_mfma_f32_16x16x32_bf16(pf[kk2], ones, acc[8], 0, 0, 0);
      }
      __builtin_amdgcn_s_setprio(0);
    }
  }

#pragma unroll
  for (int r = 0; r < 4; ++r) {
    float rl = 1.0f / acc[8][r];
    int qrow = qrow0 + lg * 4 + r;
#pragma unroll
    for (int nd = 0; nd < 8; ++nd) {
      int col = h * HD + nd * 16 + lr;
      ctx[(size_t)qrow * DM + col] = f2b(acc[nd][r] * rl);
    }
  }
}

extern "C" void kernel_launch(void* const* d_in, const int* in_sizes, int n_in,
                              void* d_out, int out_size, void* d_ws, size_t ws_size,
                              hipStream_t stream) {
  const float* x  = (const float*)d_in[0];
  const float* Wq = (const float*)d_in[1];
  const float* Wk = (const float*)d_in[2];
  const float* Wv = (const float*)d_in[3];
  const float* Wo = (const float*)d_in[4];
  const float* bo = (const float*)d_in[5];
  float* out = (float*)d_out;

  char* p = (char*)d_ws;
  bf16_t* xb    = (bf16_t*)p;                         // also reused as ctx later
  bf16_t* ctx   = xb;                                 // xb dead after QKV GEMM
  p += (size_t)SEQ * DM * 2;                          // 16.8 MB
  bf16_t* Wqkvt = (bf16_t*)p; p += (size_t)3072 * DM * 2;     // 12.6 MB (Wq^T ++ Wk^T ++ Wv^T)
  bf16_t* Wot   = (bf16_t*)p; p += (size_t)DM * DM * 2;       // 8.4 MB
  bf16_t* Qb    = (bf16_t*)p; p += (size_t)SEQ * DM * 2;      // 16.8 MB
  bf16_t* KVb   = (bf16_t*)p; p += (size_t)SEQ * 1024 * 2;    // 8.4 MB
  bf16_t* Vt    = (bf16_t*)p; p += (size_t)512 * SEQ * 2;     // 4.2 MB
  float*  ctab  = (float*)p;  p += (size_t)SEQ * 64 * 4;      // 1 MB
  float*  stab  = (float*)p;  p += (size_t)SEQ * 64 * 4;      // 1 MB

  // 1. casts / transposes (Wq->rows 0..2047, Wk->2048..2559, Wv->2560..3071)
  cast_x_bf16<<<(SEQ * DM / 4 + 255) / 256, 256, 0, stream>>>(x, xb, SEQ * DM / 4);
  transpose_cast_w<<<dim3(DM / 32, DM / 32), dim3(32, 8), 0, stream>>>(Wq, Wqkvt, DM, DM);
  transpose_cast_w<<<dim3(512 / 32, DM / 32), dim3(32, 8), 0, stream>>>(Wk, Wqkvt + (size_t)2048 * DM, DM, 512);
  transpose_cast_w<<<dim3(512 / 32, DM / 32), dim3(32, 8), 0, stream>>>(Wv, Wqkvt + (size_t)2560 * DM, DM, 512);
  transpose_cast_w<<<dim3(DM / 32, DM / 32), dim3(32, 8), 0, stream>>>(Wo, Wot, DM, DM);
  rope_tab<<<(SEQ * 64 + 255) / 256, 256, 0, stream>>>(ctab, stab);

  // 2. fused QKV projection: N=3072, split outputs (768 blocks = 3/CU)
  gemm_bt<0><<<dim3(3072 / 128, SEQ / 128), 256, 0, stream>>>(
      xb, Wqkvt, Qb, KVb, nullptr, SEQ, 3072, DM);

  // 3. RoPE (vectorized, 8 pairs/thread) + V transpose (key-permuted layout)
  rope_apply<<<(SEQ * (NH + KVH) * 8 + 255) / 256, 256, 0, stream>>>(Qb, KVb, ctab, stab);
  transpose_v<<<dim3(512 / 32, SEQ / 32), dim3(32, 8), 0, stream>>>(KVb, Vt);

  // 4. attention (ctx aliases xb region — xb no longer needed)
  attn_fwd<<<dim3(32, NH), 512, 0, stream>>>(Qb, KVb, Vt, ctx);

  // 5. output projection + bias
  gemm_bt<1><<<dim3(DM / 128, SEQ / 128), 256, 0, stream>>>(
      ctx, Wot, out, nullptr, bo, SEQ, DM, DM);
}

// Round 12
// 255.034 us; speedup vs baseline: 2.4155x; 1.0389x over previous
//
#include <hip/hip_runtime.h>
#include <cstdint>
#include <cstddef>

#define SEQ 4096
#define DM  2048
#define NH  16
#define KVH 4
#define HD  128
// softmax scale folded into Q at QKV-epilogue time: 1/sqrt(128) * log2(e)
#define QSCALE (0.08838834764831845f * 1.4426950408889634f)

typedef short bf16_t;
typedef __attribute__((ext_vector_type(8))) short bf16x8;
typedef __attribute__((ext_vector_type(4))) float f32x4;
typedef __attribute__((ext_vector_type(4))) unsigned uint32x4;

__device__ __forceinline__ bf16_t f2b(float f) {
  unsigned u = __builtin_bit_cast(unsigned, f);
  u += 0x7fffu + ((u >> 16) & 1u);          // RNE
  return (bf16_t)(u >> 16);
}
__device__ __forceinline__ float b2f(bf16_t s) {
  unsigned u = ((unsigned)(unsigned short)s) << 16;
  return __builtin_bit_cast(float, u);
}
// v_cvt_pk_bf16_f32: packs 2 f32 -> 2 bf16 (RNE) in one instr (no builtin; T12)
__device__ __forceinline__ unsigned cvtpk(float lo, float hi) {
  unsigned r;
  asm("v_cvt_pk_bf16_f32 %0, %1, %2" : "=v"(r) : "v"(lo), "v"(hi));
  return r;
}

// async global->LDS, 16B per lane. LDS dest is wave-uniform base + lane*16
// (linear); swizzling is done by permuting the per-lane GLOBAL source.
__device__ __forceinline__ void gload_lds16(const void* gsrc, void* ldst) {
  __builtin_amdgcn_global_load_lds(
      (__attribute__((address_space(1))) void*)gsrc,
      (__attribute__((address_space(3))) void*)ldst, 16, 0, 0);
}

// ---------------- fused prep: cast_x + rope table (transposed) + 4 weight transposes ----
// block ranges: [0,8192) cast_x | [8192,9216) ropeT | [9216,13312) Wq
//               [13312,14336) Wk | [14336,15360) Wv | [15360,19456) Wo
// Wq/Wk rows are PERMUTED (r' = interleave of rope pairs) so the QKV GEMM
// epilogue finds the rotation partner in the adjacent lane.
__global__ void prep(const float* __restrict__ x, bf16_t* __restrict__ xb,
                     const float* __restrict__ Wq, const float* __restrict__ Wk,
                     const float* __restrict__ Wv, const float* __restrict__ Wo,
                     bf16_t* __restrict__ Wqkvt, bf16_t* __restrict__ Wot,
                     float* __restrict__ ctT, float* __restrict__ stT) {
  __shared__ float tile[32][33];
  int bid = blockIdx.x;
  const int tid = threadIdx.x;

  if (bid < 8192) {                          // cast x -> bf16, 4 floats/thread
    int i = bid * 256 + tid;                 // n4 = SEQ*DM/4 = 2097152 exact
    float4 v = ((const float4*)x)[i];
    union { bf16_t h[4]; unsigned long long u; } o;
    o.h[0] = f2b(v.x); o.h[1] = f2b(v.y); o.h[2] = f2b(v.z); o.h[3] = f2b(v.w);
    ((unsigned long long*)xb)[i] = o.u;
    return;
  }
  bid -= 8192;
  if (bid < 1024) {                          // rope tables, TRANSPOSED [64][SEQ]
    int i = bid * 256 + tid;                 // 64*4096 = 262144 exact
    int j = i >> 12, t = i & 4095;
    float invf = expf(-(float)j * (9.210340371976184f / 64.0f)); // 10000^(-j/64)
    float ang = (float)t * invf;
    ctT[i] = cosf(ang);
    stT[i] = sinf(ang);
    return;
  }
  bid -= 1024;

  const float* W; bf16_t* Wt; int N, nx; bool perm;
  if (bid < 4096)      { W = Wq; Wt = Wqkvt;                          N = 2048; nx = 64; perm = true;  }
  else if (bid < 5120) { W = Wk; Wt = Wqkvt + (size_t)2048 * DM; bid -= 4096; N = 512; nx = 16; perm = true;  }
  else if (bid < 6144) { W = Wv; Wt = Wqkvt + (size_t)2560 * DM; bid -= 5120; N = 512; nx = 16; perm = false; }
  else                 { W = Wo; Wt = Wot;                       bid -= 6144; N = 2048; nx = 64; perm = false; }
  int bx = bid % nx, by = bid / nx;
  int k0 = by * 32, n0 = bx * 32;
  int tx = tid & 31, ty = tid >> 5;          // 32 x 8
#pragma unroll
  for (int dy = 0; dy < 32; dy += 8)
    tile[ty + dy][tx] = W[(size_t)(k0 + ty + dy) * N + n0 + tx];
  __syncthreads();
#pragma unroll
  for (int dy = 0; dy < 32; dy += 8) {
    int r = n0 + ty + dy;
    if (perm) r = (r & ~127) | ((r & 63) << 1) | ((r >> 6) & 1);  // rope-pair interleave
    Wt[(size_t)r * DM + k0 + tx] = f2b(tile[tx][ty + dy]);
  }
}

// ---------------- V half of KVb [T][1024] -> Vt [512][T], key-permuted ----------------
// Column index carries pi^-1 within each 64-key block:
//   pi(32a+8lg+4h+r) = 32a+16h+4lg+r  (PV A-slot -> true key, 16x16 pipeline)
// so P fragments after swapped-QK^T stay lane-local (pure register pack).
__global__ void transpose_v(const bf16_t* __restrict__ KVb, bf16_t* __restrict__ Vt) {
  __shared__ bf16_t tile[32][33];
  int t0 = blockIdx.y * 32, d0 = blockIdx.x * 32;
  int tx = threadIdx.x, ty = threadIdx.y;
#pragma unroll
  for (int dy = 0; dy < 32; dy += 8)
    tile[ty + dy][tx] = KVb[(size_t)(t0 + ty + dy) * 1024 + 512 + d0 + tx];
  __syncthreads();
  int tt = t0 + tx;
  int j = (tt & ~63) | (tt & 32) | ((tt & 12) << 1) | ((tt & 16) >> 2) | (tt & 3);
#pragma unroll
  for (int dy = 0; dy < 32; dy += 8)
    Vt[(size_t)(d0 + ty + dy) * SEQ + j] = tile[tx][ty + dy];
}

// ---------------- shared GEMM core: 128x128 tile, BK=64, 4 waves ----------------
// MODE 0: QKV with fused RoPE. cols [0,2048)=Q (rope+QSCALE, weights
//   interleaved), [2048,2560)=K (rope, interleaved), [2560,3072)=V (plain).
//   RoPE partner = adjacent lane (shfl_xor 1); un-interleaved col on store.
// MODE 1: fp32 out + bias, single C0 (stride N)
template <int MODE>
__global__ __launch_bounds__(256, MODE == 0 ? 3 : 2)
void gemm_bt(const bf16_t* __restrict__ A, const bf16_t* __restrict__ Bt,
             void* __restrict__ C0out, void* __restrict__ C1out,
             const float* __restrict__ bias, int M, int N, int K,
             const float* __restrict__ ctT, const float* __restrict__ stT) {
  __shared__ __align__(16) bf16_t ldsA[128 * 64];
  __shared__ __align__(16) bf16_t ldsB[128 * 64];
  const int t = threadIdx.x;
  const int w = t >> 6, l = t & 63;
  const int lg = l >> 4, lr = l & 15;
  const int bm = blockIdx.y, bn = blockIdx.x;
  const int wr = (w >> 1) * 64, wc = (w & 1) * 64;

  f32x4 acc[4][4] = {};

  for (int k0 = 0; k0 < K; k0 += 64) {
    __syncthreads();
#pragma unroll
    for (int i = 0; i < 4; ++i) {
      int idx = i * 256 + t;          // 0..1023, 16B granules
      int row = idx >> 3;             // 8 chunks per 64-col row
      int ch  = (idx & 7) ^ (row & 7);
      gload_lds16(A  + (size_t)(bm * 128 + row) * K + k0 + ch * 8, &ldsA[idx * 8]);
      gload_lds16(Bt + (size_t)(bn * 128 + row) * K + k0 + ch * 8, &ldsB[idx * 8]);
    }
    __syncthreads();
#pragma unroll
    for (int kk = 0; kk < 2; ++kk) {
      bf16x8 af[4], bfr[4];
#pragma unroll
      for (int m = 0; m < 4; ++m) {
        int row = wr + m * 16 + lr;
        int ch = (kk * 4 + lg) ^ (row & 7);
        af[m] = *(const bf16x8*)&ldsA[row * 64 + ch * 8];
      }
#pragma unroll
      for (int n = 0; n < 4; ++n) {
        int row = wc + n * 16 + lr;
        int ch = (kk * 4 + lg) ^ (row & 7);
        bfr[n] = *(const bf16x8*)&ldsB[row * 64 + ch * 8];
      }
#pragma unroll
      for (int m = 0; m < 4; ++m)
#pragma unroll
        for (int n = 0; n < 4; ++n)
          acc[m][n] = __builtin_amdgcn_mfma_f32_16x16x32_bf16(af[m], bfr[n], acc[m][n], 0, 0, 0);
    }
  }

  // D layout: col = lane&15, row = (lane>>4)*4 + r  [measured m89]
  const int row0 = bm * 128 + wr + lg * 4;
  if (MODE == 1) {
    float* C = (float*)C0out;
    const int col0 = bn * 128 + wc + lr;
#pragma unroll
    for (int n = 0; n < 4; ++n) {
      int col = col0 + n * 16;
      float b = bias[col];
#pragma unroll
      for (int m = 0; m < 4; ++m)
#pragma unroll
        for (int r = 0; r < 4; ++r)
          C[(size_t)(row0 + m * 16 + r) * N + col] = acc[m][n][r] + b;
    }
  } else {
    const int colbase = bn * 128 + wc;       // 64-aligned, head-half uniform
    if (colbase < 2560) {
      // Q or K: fused RoPE. Even lane holds j-part, odd lane (j+64)-part.
      bf16_t* C; int stride, regbase; float scl;
      if (colbase < 2048) { C = (bf16_t*)C0out; stride = 2048; regbase = 0;    scl = QSCALE; }
      else                { C = (bf16_t*)C1out; stride = 1024; regbase = 2048; scl = 1.0f;   }
      const int odd = lr & 1;
#pragma unroll
      for (int n = 0; n < 4; ++n) {
        int cpr = colbase + n * 16 + lr;     // col in interleaved space
        int j = (cpr & 127) >> 1;
        int colo = (cpr & ~127) - regbase + j + (odd ? 64 : 0);
#pragma unroll
        for (int m = 0; m < 4; ++m) {
          float4 cv = *(const float4*)&ctT[(size_t)j * SEQ + row0 + m * 16];
          float4 sv = *(const float4*)&stT[(size_t)j * SEQ + row0 + m * 16];
          float cs[4] = {cv.x, cv.y, cv.z, cv.w};
          float ss[4] = {sv.x, sv.y, sv.z, sv.w};
#pragma unroll
          for (int r = 0; r < 4; ++r) {
            float a = acc[m][n][r];
            float b = __shfl_xor(a, 1, 64);  // rotation partner (adjacent lane)
            float o = odd ? (a * cs[r] + b * ss[r]) : (a * cs[r] - b * ss[r]);
            C[(size_t)(row0 + m * 16 + r) * stride + colo] = f2b(o * scl);
          }
        }
      }
    } else {
      // V: plain bf16 store into KVb cols 512..1023
      bf16_t* C = (bf16_t*)C1out;
      const int cb = colbase - 2048;
#pragma unroll
      for (int m = 0; m < 4; ++m)
#pragma unroll
        for (int n = 0; n < 4; ++n) {
          int col = cb + n * 16 + lr;
#pragma unroll
          for (int r = 0; r < 4; ++r)
            C[(size_t)(row0 + m * 16 + r) * 1024 + col] = f2b(acc[m][n][r]);
        }
    }
  }
}

// ---------------- causal flash attention (R8 structure, verified 135 us) ----------------
// 8 waves / 512 threads per block; paired q-tiles (b, 63-b): waves 0-3 own
// q-tile b (16 rows each), waves 4-7 own q-tile 63-b -> 4 waves/SIMD at
// 2 blocks/CU. Swapped QK^T, key-permuted V (P in registers), ones-column
// row-sum, defer-max (THR=8), K+V double-buffered LDS, one barrier per tile.
__global__ __launch_bounds__(512, 4)
void attn_fwd(const bf16_t* __restrict__ Qb, const bf16_t* __restrict__ KVb,
              const bf16_t* __restrict__ Vt, bf16_t* __restrict__ ctx) {
  __shared__ __align__(16) bf16_t kt[2][64 * 128];     // K tiles, XOR-swizzled
  __shared__ __align__(16) bf16_t vts[2][128 * 64];    // V^T tiles (key-permuted), swizzled

  const int t = threadIdx.x;
  const int w = t >> 6, l = t & 63;
  const int lg = l >> 4, lr = l & 15;
  const int h = blockIdx.y, g = h >> 2;
  const int b = blockIdx.x;
  const int m = w >> 2, wq = w & 3;
  const int qt = m ? 63 - b : b;            // this wave's q-tile
  const int qrow0 = qt * 64 + wq * 16;      // wave's first q-row

  // Q fragments (B-operand after swap; row/col = lane&15, k = (lane>>4)*8+i)
  bf16x8 qf[4];
#pragma unroll
  for (int kk = 0; kk < 4; ++kk)
    qf[kk] = *(const bf16x8*)&Qb[(size_t)(qrow0 + lr) * DM + h * HD + kk * 32 + lg * 8];

  f32x4 acc[9] = {};                        // [8] = row-sum (ones column)
  float m_run = -1e30f;                     // per-lane q-row = lr (scaled units)

  bf16x8 ones;
#pragma unroll
  for (int i = 0; i < 8; ++i) ones[i] = (short)0x3F80;  // bf16 1.0

  const bf16_t* ksrc = KVb + g * 128;
  const bf16_t* vsrc = Vt + (size_t)(g * 128) * SEQ;
  auto stage = [&](int buf, int kvt) {
#pragma unroll
    for (int i = 0; i < 2; ++i) {           // K [64][128]: 1024 granules, 16/row
      int idx = i * 512 + t;
      int row = idx >> 4;
      int ch = (idx & 15) ^ (row & 7);
      gload_lds16(ksrc + (size_t)(kvt * 64 + row) * 1024 + ch * 8, &kt[buf][idx * 8]);
    }
#pragma unroll
    for (int i = 0; i < 2; ++i) {           // V^T [128][64]: 1024 granules, 8/row
      int idx = i * 512 + t;
      int row = idx >> 3;
      int ch = (idx & 7) ^ (row & 7);
      gload_lds16(vsrc + (size_t)row * SEQ + kvt * 64 + ch * 8, &vts[buf][idx * 8]);
    }
  };

  const int nkv = 64 - b;                   // qt1 + 1
  stage(0, 0);

  for (int kv = 0; kv < nkv; ++kv) {
    const int cur = kv & 1;
    const int kv0 = kv * 64;
    __syncthreads();                        // kt/vts[cur] ready (vmcnt drained)
    if (kv + 1 < nkv) stage(cur ^ 1, kv + 1);

    if (kv <= qt) {                         // causal: tile active for this wave
      // S^T = K Q^T (swapped): lane holds q = lr, key = kv0 + n*16 + lg*4 + r
      f32x4 s[4] = {};
      __builtin_amdgcn_s_setprio(1);
#pragma unroll
      for (int n = 0; n < 4; ++n) {
        int row = n * 16 + lr;
#pragma unroll
        for (int kk = 0; kk < 4; ++kk) {
          int ch = (kk * 4 + lg) ^ (row & 7);
          bf16x8 kf = *(const bf16x8*)&kt[cur][row * 128 + ch * 8];
          s[n] = __builtin_amdgcn_mfma_f32_16x16x32_bf16(kf, qf[kk], s[n], 0, 0, 0);
        }
      }
      __builtin_amdgcn_s_setprio(0);

      const int qrow = qrow0 + lr;
      if (kv == qt) {                       // diagonal tile: causal mask
#pragma unroll
        for (int n = 0; n < 4; ++n)
#pragma unroll
          for (int r = 0; r < 4; ++r) {
            int key = kv0 + n * 16 + lg * 4 + r;
            if (key > qrow) s[n][r] = -1e30f;
          }
      }

      // row max: in-lane over 16, then across the 4 lg lanes (xor 16, 32)
      float pm = s[0][0];
#pragma unroll
      for (int n = 0; n < 4; ++n)
#pragma unroll
        for (int r = 0; r < 4; ++r)
          pm = fmaxf(pm, s[n][r]);
      pm = fmaxf(pm, __shfl_xor(pm, 16, 64));
      pm = fmaxf(pm, __shfl_xor(pm, 32, 64));

      if (__any((int)(pm > m_run + 8.f))) { // defer-max (T13)
        float mn = fmaxf(m_run, pm);
        float a_s = exp2f(m_run - mn);
        m_run = mn;
        float alpha[4];
#pragma unroll
        for (int r = 0; r < 4; ++r)         // broadcast to O-domain rows lg*4+r
          alpha[r] = __shfl(a_s, (l & 48) | (lg * 4 + r), 64);
#pragma unroll
        for (int nd = 0; nd < 9; ++nd)
#pragma unroll
          for (int r = 0; r < 4; ++r)
            acc[nd][r] *= alpha[r];
      }

      // P = exp2(s - m), packed to bf16 in registers (key-permuted V layout)
      unsigned u[8];
#pragma unroll
      for (int n = 0; n < 4; ++n) {
        u[2 * n]     = cvtpk(exp2f(s[n][0] - m_run), exp2f(s[n][1] - m_run));
        u[2 * n + 1] = cvtpk(exp2f(s[n][2] - m_run), exp2f(s[n][3] - m_run));
      }
      bf16x8 pf[2];
      pf[0] = __builtin_bit_cast(bf16x8, (uint32x4){u[0], u[1], u[2], u[3]});
      pf[1] = __builtin_bit_cast(bf16x8, (uint32x4){u[4], u[5], u[6], u[7]});

      // O += P * V; row-sum via ones column
      __builtin_amdgcn_s_setprio(1);
#pragma unroll
      for (int kk2 = 0; kk2 < 2; ++kk2) {
#pragma unroll
        for (int nd = 0; nd < 8; ++nd) {
          int vrow = nd * 16 + lr;
          int vch = (kk2 * 4 + lg) ^ (lr & 7);
          bf16x8 vf = *(const bf16x8*)&vts[cur][vrow * 64 + vch * 8];
          acc[nd] = __builtin_amdgcn_mfma_f32_16x16x32_bf16(pf[kk2], vf, acc[nd], 0, 0, 0);
        }
        acc[8] = __builtin_amdgcn_mfma_f32_16x16x32_bf16(pf[kk2], ones, acc[8], 0, 0, 0);
      }
      __builtin_amdgcn_s_setprio(0);
    }
  }

#pragma unroll
  for (int r = 0; r < 4; ++r) {
    float rl = 1.0f / acc[8][r];
    int qrow = qrow0 + lg * 4 + r;
#pragma unroll
    for (int nd = 0; nd < 8; ++nd) {
      int col = h * HD + nd * 16 + lr;
      ctx[(size_t)qrow * DM + col] = f2b(acc[nd][r] * rl);
    }
  }
}

extern "C" void kernel_launch(void* const* d_in, const int* in_sizes, int n_in,
                              void* d_out, int out_size, void* d_ws, size_t ws_size,
                              hipStream_t stream) {
  const float* x  = (const float*)d_in[0];
  const float* Wq = (const float*)d_in[1];
  const float* Wk = (const float*)d_in[2];
  const float* Wv = (const float*)d_in[3];
  const float* Wo = (const float*)d_in[4];
  const float* bo = (const float*)d_in[5];
  float* out = (float*)d_out;

  char* p = (char*)d_ws;
  bf16_t* xb    = (bf16_t*)p;                         // also reused as ctx later
  bf16_t* ctx   = xb;                                 // xb dead after QKV GEMM
  p += (size_t)SEQ * DM * 2;                          // 16.8 MB
  bf16_t* Wqkvt = (bf16_t*)p; p += (size_t)3072 * DM * 2;     // 12.6 MB (Wq^T ++ Wk^T ++ Wv^T)
  bf16_t* Wot   = (bf16_t*)p; p += (size_t)DM * DM * 2;       // 8.4 MB
  bf16_t* Qb    = (bf16_t*)p; p += (size_t)SEQ * DM * 2;      // 16.8 MB
  bf16_t* KVb   = (bf16_t*)p; p += (size_t)SEQ * 1024 * 2;    // 8.4 MB
  bf16_t* Vt    = (bf16_t*)p; p += (size_t)512 * SEQ * 2;     // 4.2 MB
  float*  ctT   = (float*)p;  p += (size_t)64 * SEQ * 4;      // 1 MB, [64][SEQ]
  float*  stT   = (float*)p;  p += (size_t)64 * SEQ * 4;      // 1 MB

  // 1. fused prep: cast x, build transposed rope tables, pack/transpose all
  //    weights (Wq/Wk rows rope-pair-interleaved for the fused epilogue)
  prep<<<19456, 256, 0, stream>>>(x, xb, Wq, Wk, Wv, Wo, Wqkvt, Wot, ctT, stT);

  // 2. fused QKV projection + RoPE epilogue (768 blocks = 3/CU)
  gemm_bt<0><<<dim3(3072 / 128, SEQ / 128), 256, 0, stream>>>(
      xb, Wqkvt, Qb, KVb, nullptr, SEQ, 3072, DM, ctT, stT);

  // 3. V transpose (key-permuted layout)
  transpose_v<<<dim3(512 / 32, SEQ / 32), dim3(32, 8), 0, stream>>>(KVb, Vt);

  // 4. attention (ctx aliases xb region — xb no longer needed)
  attn_fwd<<<dim3(32, NH), 512, 0, stream>>>(Qb, KVb, Vt, ctx);

  // 5. output projection + bias
  gemm_bt<1><<<dim3(DM / 128, SEQ / 128), 256, 0, stream>>>(
      ctx, Wot, out, nullptr, bo, SEQ, DM, DM, nullptr, nullptr);
}

// Round 13
// 251.146 us; speedup vs baseline: 2.4529x; 1.0155x over previous
//
#include <hip/hip_runtime.h>
#include <cstdint>
#include <cstddef>

#define SEQ 4096
#define DM  2048
#define NH  16
#define KVH 4
#define HD  128
// softmax scale folded into Q at QKV-epilogue time: 1/sqrt(128) * log2(e)
#define QSCALE (0.08838834764831845f * 1.4426950408889634f)

typedef short bf16_t;
typedef __attribute__((ext_vector_type(8))) short bf16x8;
typedef __attribute__((ext_vector_type(4))) float f32x4;
typedef __attribute__((ext_vector_type(4))) unsigned uint32x4;

__device__ __forceinline__ bf16_t f2b(float f) {
  unsigned u = __builtin_bit_cast(unsigned, f);
  u += 0x7fffu + ((u >> 16) & 1u);          // RNE
  return (bf16_t)(u >> 16);
}
__device__ __forceinline__ float b2f(bf16_t s) {
  unsigned u = ((unsigned)(unsigned short)s) << 16;
  return __builtin_bit_cast(float, u);
}
// v_cvt_pk_bf16_f32: packs 2 f32 -> 2 bf16 (RNE) in one instr (no builtin; T12)
__device__ __forceinline__ unsigned cvtpk(float lo, float hi) {
  unsigned r;
  asm("v_cvt_pk_bf16_f32 %0, %1, %2" : "=v"(r) : "v"(lo), "v"(hi));
  return r;
}

// async global->LDS, 16B per lane. LDS dest is wave-uniform base + lane*16
// (linear); swizzling is done by permuting the per-lane GLOBAL source.
__device__ __forceinline__ void gload_lds16(const void* gsrc, void* ldst) {
  __builtin_amdgcn_global_load_lds(
      (__attribute__((address_space(1))) void*)gsrc,
      (__attribute__((address_space(3))) void*)ldst, 16, 0, 0);
}

// ---------------- fused prep: cast_x + rope table (transposed) + 4 weight transposes ----
// block ranges: [0,8192) cast_x | [8192,9216) ropeT | [9216,13312) Wq
//               [13312,14336) Wk | [14336,15360) Wv | [15360,19456) Wo
// Wq/Wk rows are PERMUTED (r' = interleave of rope pairs) so the QKV GEMM
// epilogue finds the rotation partner in the adjacent lane.
__global__ void prep(const float* __restrict__ x, bf16_t* __restrict__ xb,
                     const float* __restrict__ Wq, const float* __restrict__ Wk,
                     const float* __restrict__ Wv, const float* __restrict__ Wo,
                     bf16_t* __restrict__ Wqkvt, bf16_t* __restrict__ Wot,
                     float* __restrict__ ctT, float* __restrict__ stT) {
  __shared__ float tile[32][33];
  int bid = blockIdx.x;
  const int tid = threadIdx.x;

  if (bid < 8192) {                          // cast x -> bf16, 4 floats/thread
    int i = bid * 256 + tid;                 // n4 = SEQ*DM/4 = 2097152 exact
    float4 v = ((const float4*)x)[i];
    union { bf16_t h[4]; unsigned long long u; } o;
    o.h[0] = f2b(v.x); o.h[1] = f2b(v.y); o.h[2] = f2b(v.z); o.h[3] = f2b(v.w);
    ((unsigned long long*)xb)[i] = o.u;
    return;
  }
  bid -= 8192;
  if (bid < 1024) {                          // rope tables, TRANSPOSED [64][SEQ]
    int i = bid * 256 + tid;                 // 64*4096 = 262144 exact
    int j = i >> 12, t = i & 4095;
    float invf = expf(-(float)j * (9.210340371976184f / 64.0f)); // 10000^(-j/64)
    float ang = (float)t * invf;
    ctT[i] = cosf(ang);
    stT[i] = sinf(ang);
    return;
  }
  bid -= 1024;

  const float* W; bf16_t* Wt; int N, nx; bool perm;
  if (bid < 4096)      { W = Wq; Wt = Wqkvt;                          N = 2048; nx = 64; perm = true;  }
  else if (bid < 5120) { W = Wk; Wt = Wqkvt + (size_t)2048 * DM; bid -= 4096; N = 512; nx = 16; perm = true;  }
  else if (bid < 6144) { W = Wv; Wt = Wqkvt + (size_t)2560 * DM; bid -= 5120; N = 512; nx = 16; perm = false; }
  else                 { W = Wo; Wt = Wot;                       bid -= 6144; N = 2048; nx = 64; perm = false; }
  int bx = bid % nx, by = bid / nx;
  int k0 = by * 32, n0 = bx * 32;
  int tx = tid & 31, ty = tid >> 5;          // 32 x 8
#pragma unroll
  for (int dy = 0; dy < 32; dy += 8)
    tile[ty + dy][tx] = W[(size_t)(k0 + ty + dy) * N + n0 + tx];
  __syncthreads();
#pragma unroll
  for (int dy = 0; dy < 32; dy += 8) {
    int r = n0 + ty + dy;
    if (perm) r = (r & ~127) | ((r & 63) << 1) | ((r >> 6) & 1);  // rope-pair interleave
    Wt[(size_t)r * DM + k0 + tx] = f2b(tile[tx][ty + dy]);
  }
}

// ---------------- shared GEMM core: 128x128 tile, BK=64, 4 waves ----------------
// MODE 0: QKV fused epilogue. cols [0,2048)=Q (rope+QSCALE, weights
//   interleaved, ->C0 Qb stride 2048), [2048,2560)=K (rope, interleaved,
//   ->C1 Kb stride 512), [2560,3072)=V (->C2 Vt DIRECT, transposed +
//   key-permuted: j = (t&~63)|((m&2)<<4)|(lg<<3)|((m&1)<<2)|r, one 8B
//   store of 4 consecutive tokens per (m,n)).
// MODE 1: fp32 out + bias, single C0 (stride N)
template <int MODE>
__global__ __launch_bounds__(256, MODE == 0 ? 3 : 2)
void gemm_bt(const bf16_t* __restrict__ A, const bf16_t* __restrict__ Bt,
             void* __restrict__ C0out, void* __restrict__ C1out,
             void* __restrict__ C2out,
             const float* __restrict__ bias, int M, int N, int K,
             const float* __restrict__ ctT, const float* __restrict__ stT) {
  __shared__ __align__(16) bf16_t ldsA[128 * 64];
  __shared__ __align__(16) bf16_t ldsB[128 * 64];
  const int t = threadIdx.x;
  const int w = t >> 6, l = t & 63;
  const int lg = l >> 4, lr = l & 15;
  const int bm = blockIdx.y, bn = blockIdx.x;
  const int wr = (w >> 1) * 64, wc = (w & 1) * 64;

  f32x4 acc[4][4] = {};

  for (int k0 = 0; k0 < K; k0 += 64) {
    __syncthreads();
#pragma unroll
    for (int i = 0; i < 4; ++i) {
      int idx = i * 256 + t;          // 0..1023, 16B granules
      int row = idx >> 3;             // 8 chunks per 64-col row
      int ch  = (idx & 7) ^ (row & 7);
      gload_lds16(A  + (size_t)(bm * 128 + row) * K + k0 + ch * 8, &ldsA[idx * 8]);
      gload_lds16(Bt + (size_t)(bn * 128 + row) * K + k0 + ch * 8, &ldsB[idx * 8]);
    }
    __syncthreads();
#pragma unroll
    for (int kk = 0; kk < 2; ++kk) {
      bf16x8 af[4], bfr[4];
#pragma unroll
      for (int m = 0; m < 4; ++m) {
        int row = wr + m * 16 + lr;
        int ch = (kk * 4 + lg) ^ (row & 7);
        af[m] = *(const bf16x8*)&ldsA[row * 64 + ch * 8];
      }
#pragma unroll
      for (int n = 0; n < 4; ++n) {
        int row = wc + n * 16 + lr;
        int ch = (kk * 4 + lg) ^ (row & 7);
        bfr[n] = *(const bf16x8*)&ldsB[row * 64 + ch * 8];
      }
#pragma unroll
      for (int m = 0; m < 4; ++m)
#pragma unroll
        for (int n = 0; n < 4; ++n)
          acc[m][n] = __builtin_amdgcn_mfma_f32_16x16x32_bf16(af[m], bfr[n], acc[m][n], 0, 0, 0);
    }
  }

  // D layout: col = lane&15, row = (lane>>4)*4 + r  [measured m89]
  const int row0 = bm * 128 + wr + lg * 4;
  if (MODE == 1) {
    float* C = (float*)C0out;
    const int col0 = bn * 128 + wc + lr;
#pragma unroll
    for (int n = 0; n < 4; ++n) {
      int col = col0 + n * 16;
      float b = bias[col];
#pragma unroll
      for (int m = 0; m < 4; ++m)
#pragma unroll
        for (int r = 0; r < 4; ++r)
          C[(size_t)(row0 + m * 16 + r) * N + col] = acc[m][n][r] + b;
    }
  } else {
    const int colbase = bn * 128 + wc;       // 64-aligned, head-half uniform
    if (colbase < 2560) {
      // Q or K: fused RoPE. Even lane holds j-part, odd lane (j+64)-part.
      bf16_t* C; int stride, regbase; float scl;
      if (colbase < 2048) { C = (bf16_t*)C0out; stride = 2048; regbase = 0;    scl = QSCALE; }
      else                { C = (bf16_t*)C1out; stride = 512;  regbase = 2048; scl = 1.0f;   }
      const int odd = lr & 1;
#pragma unroll
      for (int n = 0; n < 4; ++n) {
        int cpr = colbase + n * 16 + lr;     // col in interleaved space
        int j = (cpr & 127) >> 1;
        int colo = (cpr & ~127) - regbase + j + (odd ? 64 : 0);
#pragma unroll
        for (int m = 0; m < 4; ++m) {
          float4 cv = *(const float4*)&ctT[(size_t)j * SEQ + row0 + m * 16];
          float4 sv = *(const float4*)&stT[(size_t)j * SEQ + row0 + m * 16];
          float cs[4] = {cv.x, cv.y, cv.z, cv.w};
          float ss[4] = {sv.x, sv.y, sv.z, sv.w};
#pragma unroll
          for (int r = 0; r < 4; ++r) {
            float a = acc[m][n][r];
            float b = __shfl_xor(a, 1, 64);  // rotation partner (adjacent lane)
            float o = odd ? (a * cs[r] + b * ss[r]) : (a * cs[r] - b * ss[r]);
            C[(size_t)(row0 + m * 16 + r) * stride + colo] = f2b(o * scl);
          }
        }
      }
    } else {
      // V: DIRECT store to Vt [512][SEQ], transposed + key-permuted.
      // t = bm*128 + wr + m*16 + lg*4 + r; within-64 permutation maps to
      // j = (t&~63) | ((m&2)<<4) | (lg<<3) | ((m&1)<<2) | r  (r contiguous
      // -> one 8B store of 4 tokens).
      bf16_t* Vt = (bf16_t*)C2out;
      const int dbase = colbase - 2560;
      const int jb = bm * 128 + wr;
#pragma unroll
      for (int m = 0; m < 4; ++m) {
        int j = jb | ((m & 2) << 4) | (lg << 3) | ((m & 1) << 2);
#pragma unroll
        for (int n = 0; n < 4; ++n) {
          int d = dbase + n * 16 + lr;
          unsigned lo = cvtpk(acc[m][n][0], acc[m][n][1]);
          unsigned hi = cvtpk(acc[m][n][2], acc[m][n][3]);
          unsigned long long uv = ((unsigned long long)hi << 32) | lo;
          *(unsigned long long*)&Vt[(size_t)d * SEQ + j] = uv;
        }
      }
    }
  }
}

// ---------------- causal flash attention (R8 structure, verified 135 us) ----------------
// 8 waves / 512 threads per block; paired q-tiles (b, 63-b): waves 0-3 own
// q-tile b (16 rows each), waves 4-7 own q-tile 63-b -> 4 waves/SIMD at
// 2 blocks/CU. Swapped QK^T, key-permuted V (P in registers), ones-column
// row-sum, defer-max (THR=8), K+V double-buffered LDS, one barrier per tile.
// K now lives in Kb [SEQ][512] (K-only buffer, stride 512).
__global__ __launch_bounds__(512, 4)
void attn_fwd(const bf16_t* __restrict__ Qb, const bf16_t* __restrict__ Kb,
              const bf16_t* __restrict__ Vt, bf16_t* __restrict__ ctx) {
  __shared__ __align__(16) bf16_t kt[2][64 * 128];     // K tiles, XOR-swizzled
  __shared__ __align__(16) bf16_t vts[2][128 * 64];    // V^T tiles (key-permuted), swizzled

  const int t = threadIdx.x;
  const int w = t >> 6, l = t & 63;
  const int lg = l >> 4, lr = l & 15;
  const int h = blockIdx.y, g = h >> 2;
  const int b = blockIdx.x;
  const int m = w >> 2, wq = w & 3;
  const int qt = m ? 63 - b : b;            // this wave's q-tile
  const int qrow0 = qt * 64 + wq * 16;      // wave's first q-row

  // Q fragments (B-operand after swap; row/col = lane&15, k = (lane>>4)*8+i)
  bf16x8 qf[4];
#pragma unroll
  for (int kk = 0; kk < 4; ++kk)
    qf[kk] = *(const bf16x8*)&Qb[(size_t)(qrow0 + lr) * DM + h * HD + kk * 32 + lg * 8];

  f32x4 acc[9] = {};                        // [8] = row-sum (ones column)
  float m_run = -1e30f;                     // per-lane q-row = lr (scaled units)

  bf16x8 ones;
#pragma unroll
  for (int i = 0; i < 8; ++i) ones[i] = (short)0x3F80;  // bf16 1.0

  const bf16_t* ksrc = Kb + g * 128;
  const bf16_t* vsrc = Vt + (size_t)(g * 128) * SEQ;
  auto stage = [&](int buf, int kvt) {
#pragma unroll
    for (int i = 0; i < 2; ++i) {           // K [64][128]: 1024 granules, 16/row
      int idx = i * 512 + t;
      int row = idx >> 4;
      int ch = (idx & 15) ^ (row & 7);
      gload_lds16(ksrc + (size_t)(kvt * 64 + row) * 512 + ch * 8, &kt[buf][idx * 8]);
    }
#pragma unroll
    for (int i = 0; i < 2; ++i) {           // V^T [128][64]: 1024 granules, 8/row
      int idx = i * 512 + t;
      int row = idx >> 3;
      int ch = (idx & 7) ^ (row & 7);
      gload_lds16(vsrc + (size_t)row * SEQ + kvt * 64 + ch * 8, &vts[buf][idx * 8]);
    }
  };

  const int nkv = 64 - b;                   // qt1 + 1
  stage(0, 0);

  for (int kv = 0; kv < nkv; ++kv) {
    const int cur = kv & 1;
    const int kv0 = kv * 64;
    __syncthreads();                        // kt/vts[cur] ready (vmcnt drained)
    if (kv + 1 < nkv) stage(cur ^ 1, kv + 1);

    if (kv <= qt) {                         // causal: tile active for this wave
      // S^T = K Q^T (swapped): lane holds q = lr, key = kv0 + n*16 + lg*4 + r
      f32x4 s[4] = {};
      __builtin_amdgcn_s_setprio(1);
#pragma unroll
      for (int n = 0; n < 4; ++n) {
        int row = n * 16 + lr;
#pragma unroll
        for (int kk = 0; kk < 4; ++kk) {
          int ch = (kk * 4 + lg) ^ (row & 7);
          bf16x8 kf = *(const bf16x8*)&kt[cur][row * 128 + ch * 8];
          s[n] = __builtin_amdgcn_mfma_f32_16x16x32_bf16(kf, qf[kk], s[n], 0, 0, 0);
        }
      }
      __builtin_amdgcn_s_setprio(0);

      const int qrow = qrow0 + lr;
      if (kv == qt) {                       // diagonal tile: causal mask
#pragma unroll
        for (int n = 0; n < 4; ++n)
#pragma unroll
          for (int r = 0; r < 4; ++r) {
            int key = kv0 + n * 16 + lg * 4 + r;
            if (key > qrow) s[n][r] = -1e30f;
          }
      }

      // row max: in-lane over 16, then across the 4 lg lanes (xor 16, 32)
      float pm = s[0][0];
#pragma unroll
      for (int n = 0; n < 4; ++n)
#pragma unroll
        for (int r = 0; r < 4; ++r)
          pm = fmaxf(pm, s[n][r]);
      pm = fmaxf(pm, __shfl_xor(pm, 16, 64));
      pm = fmaxf(pm, __shfl_xor(pm, 32, 64));

      if (__any((int)(pm > m_run + 8.f))) { // defer-max (T13)
        float mn = fmaxf(m_run, pm);
        float a_s = exp2f(m_run - mn);
        m_run = mn;
        float alpha[4];
#pragma unroll
        for (int r = 0; r < 4; ++r)         // broadcast to O-domain rows lg*4+r
          alpha[r] = __shfl(a_s, (l & 48) | (lg * 4 + r), 64);
#pragma unroll
        for (int nd = 0; nd < 9; ++nd)
#pragma unroll
          for (int r = 0; r < 4; ++r)
            acc[nd][r] *= alpha[r];
      }

      // P = exp2(s - m), packed to bf16 in registers (key-permuted V layout)
      unsigned u[8];
#pragma unroll
      for (int n = 0; n < 4; ++n) {
        u[2 * n]     = cvtpk(exp2f(s[n][0] - m_run), exp2f(s[n][1] - m_run));
        u[2 * n + 1] = cvtpk(exp2f(s[n][2] - m_run), exp2f(s[n][3] - m_run));
      }
      bf16x8 pf[2];
      pf[0] = __builtin_bit_cast(bf16x8, (uint32x4){u[0], u[1], u[2], u[3]});
      pf[1] = __builtin_bit_cast(bf16x8, (uint32x4){u[4], u[5], u[6], u[7]});

      // O += P * V; row-sum via ones column
      __builtin_amdgcn_s_setprio(1);
#pragma unroll
      for (int kk2 = 0; kk2 < 2; ++kk2) {
#pragma unroll
        for (int nd = 0; nd < 8; ++nd) {
          int vrow = nd * 16 + lr;
          int vch = (kk2 * 4 + lg) ^ (lr & 7);
          bf16x8 vf = *(const bf16x8*)&vts[cur][vrow * 64 + vch * 8];
          acc[nd] = __builtin_amdgcn_mfma_f32_16x16x32_bf16(pf[kk2], vf, acc[nd], 0, 0, 0);
        }
        acc[8] = __builtin_amdgcn_mfma_f32_16x16x32_bf16(pf[kk2], ones, acc[8], 0, 0, 0);
      }
      __builtin_amdgcn_s_setprio(0);
    }
  }

#pragma unroll
  for (int r = 0; r < 4; ++r) {
    float rl = 1.0f / acc[8][r];
    int qrow = qrow0 + lg * 4 + r;
#pragma unroll
    for (int nd = 0; nd < 8; ++nd) {
      int col = h * HD + nd * 16 + lr;
      ctx[(size_t)qrow * DM + col] = f2b(acc[nd][r] * rl);
    }
  }
}

extern "C" void kernel_launch(void* const* d_in, const int* in_sizes, int n_in,
                              void* d_out, int out_size, void* d_ws, size_t ws_size,
                              hipStream_t stream) {
  const float* x  = (const float*)d_in[0];
  const float* Wq = (const float*)d_in[1];
  const float* Wk = (const float*)d_in[2];
  const float* Wv = (const float*)d_in[3];
  const float* Wo = (const float*)d_in[4];
  const float* bo = (const float*)d_in[5];
  float* out = (float*)d_out;

  char* p = (char*)d_ws;
  bf16_t* xb    = (bf16_t*)p;                         // also reused as ctx later
  bf16_t* ctx   = xb;                                 // xb dead after QKV GEMM
  p += (size_t)SEQ * DM * 2;                          // 16.8 MB
  bf16_t* Wqkvt = (bf16_t*)p; p += (size_t)3072 * DM * 2;     // 12.6 MB (Wq^T ++ Wk^T ++ Wv^T)
  bf16_t* Wot   = (bf16_t*)p; p += (size_t)DM * DM * 2;       // 8.4 MB
  bf16_t* Qb    = (bf16_t*)p; p += (size_t)SEQ * DM * 2;      // 16.8 MB
  bf16_t* Kb    = (bf16_t*)p; p += (size_t)SEQ * 512 * 2;     // 4.2 MB (K only)
  bf16_t* Vt    = (bf16_t*)p; p += (size_t)512 * SEQ * 2;     // 4.2 MB
  float*  ctT   = (float*)p;  p += (size_t)64 * SEQ * 4;      // 1 MB, [64][SEQ]
  float*  stT   = (float*)p;  p += (size_t)64 * SEQ * 4;      // 1 MB

  // 1. fused prep: cast x, build transposed rope tables, pack/transpose all
  //    weights (Wq/Wk rows rope-pair-interleaved for the fused epilogue)
  prep<<<19456, 256, 0, stream>>>(x, xb, Wq, Wk, Wv, Wo, Wqkvt, Wot, ctT, stT);

  // 2. fused QKV projection + RoPE epilogue + direct V-transpose epilogue
  gemm_bt<0><<<dim3(3072 / 128, SEQ / 128), 256, 0, stream>>>(
      xb, Wqkvt, Qb, Kb, Vt, nullptr, SEQ, 3072, DM, ctT, stT);

  // 3. attention (ctx aliases xb region — xb no longer needed)
  attn_fwd<<<dim3(32, NH), 512, 0, stream>>>(Qb, Kb, Vt, ctx);

  // 4. output projection + bias
  gemm_bt<1><<<dim3(DM / 128, SEQ / 128), 256, 0, stream>>>(
      ctx, Wot, out, nullptr, nullptr, bo, SEQ, DM, DM, nullptr, nullptr);
}